// Round 5
// baseline (1118.585 us; speedup 1.0000x reference)
//
#include <hip/hip_runtime.h>

// AudioMamba forward, fp32 activations; big GEMMs via split-bf16 MFMA
// (hi/lo decomposition, 3 MFMAs, fp32-accurate). Inputs fp32, output fp32.
// B=4, L=256, D_MODEL=512, D_INNER=1024, S=16, R=32, DEPTH=4.

#define BB 4
#define LL 256
#define DM 512
#define DI 1024

typedef unsigned short u16;
typedef unsigned int u32;
typedef __attribute__((ext_vector_type(8))) short s8v;   // 8 bf16 (4 VGPRs)
typedef __attribute__((ext_vector_type(4))) float f4v;   // MFMA accumulator

__device__ __forceinline__ float silu_f(float x){ return x/(1.f+__expf(-x)); }
__device__ __forceinline__ float b2f(u16 u){
  union { u32 i; float f; } v; v.i = ((u32)u) << 16; return v.f;
}
__device__ __forceinline__ u16 f2bf(float f){
  union { float f; u32 u; } v; v.f = f;
  u32 r = (v.u + 0x7fffu + ((v.u >> 16) & 1u)) >> 16;
  return (u16)r;
}
// split 8 fp32 into hi/lo bf16 fragments (v ~= hi + lo to ~2^-17 rel)
__device__ __forceinline__ void split8(const float* f, s8v& hi, s8v& lo){
#pragma unroll
  for (int j = 0; j < 8; ++j){
    u16 h = f2bf(f[j]);
    float hf = b2f(h);
    hi[j] = (short)h;
    lo[j] = (short)f2bf(f[j] - hf);
  }
}

__device__ __forceinline__ void block_reduce2(float& a, float& b, float* sc, int nw){
  int lane = threadIdx.x & 63, wid = threadIdx.x >> 6;
#pragma unroll
  for (int o = 32; o > 0; o >>= 1){
    a += __shfl_down(a, o, 64);
    b += __shfl_down(b, o, 64);
  }
  if (lane == 0){ sc[wid*2] = a; sc[wid*2+1] = b; }
  __syncthreads();
  float ta = 0.f, tb = 0.f;
  for (int i = 0; i < nw; ++i){ ta += sc[i*2]; tb += sc[i*2+1]; }
  a = ta; b = tb;
}

// ---- patch embed: 128 blocks (b4, ph8, pg4); each block does 8 tokens ----
__global__ __launch_bounds__(256) void patch_embed(const float* __restrict__ x,
    const float* __restrict__ pw, const float* __restrict__ pb, float* __restrict__ h){
  __shared__ float xs[8*256];
  int blk = blockIdx.x;
  int b = blk >> 5, ph = (blk >> 2) & 7, pg = blk & 3;
  int t = threadIdx.x;
  for (int idx = t; idx < 2048; idx += 256){
    int j = idx >> 8, pix = idx & 255, p = pix >> 4, q = pix & 15;
    xs[idx] = x[(size_t)(b*128 + ph*16 + p)*512 + pg*128 + j*16 + q];
  }
  __syncthreads();
  for (int dd = 0; dd < 2; ++dd){
    int d = t + dd*256;
    float acc[8] = {};
    const float* wr = pw + (size_t)d*256;
    for (int i = 0; i < 256; i += 8){
      float4 w0 = *(const float4*)(wr + i);
      float4 w1 = *(const float4*)(wr + i + 4);
      float wf[8] = {w0.x,w0.y,w0.z,w0.w,w1.x,w1.y,w1.z,w1.w};
#pragma unroll
      for (int j = 0; j < 8; ++j){
#pragma unroll
        for (int jj = 0; jj < 8; ++jj)
          acc[j] = fmaf(xs[j*256 + i + jj], wf[jj], acc[j]);
      }
    }
    float bias = pb[d];
#pragma unroll
    for (int j = 0; j < 8; ++j)
      h[(size_t)(b*256 + ph*32 + pg*8 + j)*512 + d] = acc[j] + bias;
  }
}

// ---- in_proj via MFMA, LN fused into A-load ----
// C(1024,2048) = LN(X)(1024,512) @ W(2048,512)^T ; split-bf16 x3 MFMA
__global__ __launch_bounds__(256) void gemm1_ln_mfma(const float* __restrict__ X,
    const float* __restrict__ lnw, const float* __restrict__ lnb, int lnOff,
    const float* __restrict__ W, int wOff, float* __restrict__ C){
  __shared__ float rmean[64], rrstd[64];
  int bm = blockIdx.y*64, bn = blockIdx.x*64;
  int t = threadIdx.x;
  { // LN row stats for the 64 A-rows
    int lr = t >> 2, lq = t & 3;
    const float* xr = X + (size_t)(bm + lr)*512 + lq*128;
    float s = 0.f, ss = 0.f;
    for (int i = 0; i < 128; i += 4){
      float4 v = *(const float4*)(xr + i);
      s  += v.x + v.y + v.z + v.w;
      ss += v.x*v.x + v.y*v.y + v.z*v.z + v.w*v.w;
    }
    s += __shfl_xor(s, 1, 64); ss += __shfl_xor(ss, 1, 64);
    s += __shfl_xor(s, 2, 64); ss += __shfl_xor(ss, 2, 64);
    if (lq == 0){
      float m = s * (1.f/512.f);
      float var = ss * (1.f/512.f) - m*m;
      rmean[lr] = m; rrstd[lr] = rsqrtf(var + 1e-5f);
    }
  }
  __syncthreads();
  int w = t >> 6, lane = t & 63, ml = lane & 15, quad = lane >> 4;
  int m = bm + w*16 + ml;
  float mm = rmean[w*16 + ml], rr = rrstd[w*16 + ml];
  f4v acc[4] = {};
  for (int k0 = 0; k0 < 512; k0 += 32){
    int k = k0 + quad*8;
    float4 a0 = *(const float4*)(X + (size_t)m*512 + k);
    float4 a1 = *(const float4*)(X + (size_t)m*512 + k + 4);
    float4 g0 = *(const float4*)(lnw + lnOff + k);
    float4 g1 = *(const float4*)(lnw + lnOff + k + 4);
    float4 c0 = *(const float4*)(lnb + lnOff + k);
    float4 c1 = *(const float4*)(lnb + lnOff + k + 4);
    float af[8] = {
      (a0.x-mm)*rr*g0.x + c0.x, (a0.y-mm)*rr*g0.y + c0.y,
      (a0.z-mm)*rr*g0.z + c0.z, (a0.w-mm)*rr*g0.w + c0.w,
      (a1.x-mm)*rr*g1.x + c1.x, (a1.y-mm)*rr*g1.y + c1.y,
      (a1.z-mm)*rr*g1.z + c1.z, (a1.w-mm)*rr*g1.w + c1.w };
    s8v ahi, alo; split8(af, ahi, alo);
#pragma unroll
    for (int nt = 0; nt < 4; ++nt){
      const float* wr = W + wOff + (size_t)(bn + nt*16 + ml)*512 + k;
      float4 b0 = *(const float4*)wr;
      float4 b1 = *(const float4*)(wr + 4);
      float bf[8] = {b0.x,b0.y,b0.z,b0.w,b1.x,b1.y,b1.z,b1.w};
      s8v bhi, blo; split8(bf, bhi, blo);
      acc[nt] = __builtin_amdgcn_mfma_f32_16x16x32_bf16(ahi, bhi, acc[nt], 0, 0, 0);
      acc[nt] = __builtin_amdgcn_mfma_f32_16x16x32_bf16(alo, bhi, acc[nt], 0, 0, 0);
      acc[nt] = __builtin_amdgcn_mfma_f32_16x16x32_bf16(ahi, blo, acc[nt], 0, 0, 0);
    }
  }
#pragma unroll
  for (int nt = 0; nt < 4; ++nt)
#pragma unroll
    for (int r = 0; r < 4; ++r)
      C[(size_t)(bm + w*16 + quad*4 + r)*2048 + bn + nt*16 + ml] = acc[nt][r];
}

// ---- out_proj via MFMA, gate fused into A-load, residual +=  ----
// C(1024,512) += [(yf+yb)*silu(z)](1024,1024) @ W(512,1024)^T
__global__ __launch_bounds__(256) void gemm2_gate_mfma(const float* __restrict__ yb2,
    const float* __restrict__ xz, const float* __restrict__ W, int wOff,
    float* __restrict__ C){
  int bm = blockIdx.y*64, bn = blockIdx.x*64;
  int t = threadIdx.x;
  int w = t >> 6, lane = t & 63, ml = lane & 15, quad = lane >> 4;
  int m = bm + w*16 + ml;
  f4v acc[4] = {};
  for (int k0 = 0; k0 < 1024; k0 += 32){
    int k = k0 + quad*8;
    float4 f0 = *(const float4*)(yb2 + (size_t)m*DI + k);
    float4 f1 = *(const float4*)(yb2 + (size_t)m*DI + k + 4);
    float4 r0 = *(const float4*)(yb2 + (size_t)(1024 + m)*DI + k);
    float4 r1 = *(const float4*)(yb2 + (size_t)(1024 + m)*DI + k + 4);
    float4 z0 = *(const float4*)(xz + (size_t)m*2048 + 1024 + k);
    float4 z1 = *(const float4*)(xz + (size_t)m*2048 + 1024 + k + 4);
    float af[8] = {
      (f0.x+r0.x)*silu_f(z0.x), (f0.y+r0.y)*silu_f(z0.y),
      (f0.z+r0.z)*silu_f(z0.z), (f0.w+r0.w)*silu_f(z0.w),
      (f1.x+r1.x)*silu_f(z1.x), (f1.y+r1.y)*silu_f(z1.y),
      (f1.z+r1.z)*silu_f(z1.z), (f1.w+r1.w)*silu_f(z1.w) };
    s8v ahi, alo; split8(af, ahi, alo);
#pragma unroll
    for (int nt = 0; nt < 4; ++nt){
      const float* wr = W + wOff + (size_t)(bn + nt*16 + ml)*1024 + k;
      float4 b0 = *(const float4*)wr;
      float4 b1 = *(const float4*)(wr + 4);
      float bf[8] = {b0.x,b0.y,b0.z,b0.w,b1.x,b1.y,b1.z,b1.w};
      s8v bhi, blo; split8(bf, bhi, blo);
      acc[nt] = __builtin_amdgcn_mfma_f32_16x16x32_bf16(ahi, bhi, acc[nt], 0, 0, 0);
      acc[nt] = __builtin_amdgcn_mfma_f32_16x16x32_bf16(alo, bhi, acc[nt], 0, 0, 0);
      acc[nt] = __builtin_amdgcn_mfma_f32_16x16x32_bf16(ahi, blo, acc[nt], 0, 0, 0);
    }
  }
#pragma unroll
  for (int nt = 0; nt < 4; ++nt)
#pragma unroll
    for (int r = 0; r < 4; ++r){
      float* cp = C + (size_t)(bm + w*16 + quad*4 + r)*512 + bn + nt*16 + ml;
      *cp += acc[nt][r];
    }
}

// ---- fused conv+silu -> xproj -> dtproj+softplus; block per (dir,b, 4 l's) ----
__global__ __launch_bounds__(256) void fused_cxd(const float* __restrict__ xz,
    const float* __restrict__ cwF, const float* __restrict__ cbF,
    const float* __restrict__ cwB, const float* __restrict__ cbB,
    const float* __restrict__ xwF, const float* __restrict__ xwB,
    const float* __restrict__ dtwF, const float* __restrict__ dtbF,
    const float* __restrict__ dtwB, const float* __restrict__ dtbB,
    int cwOff, int cbOff, int xwOff, int dtwOff, int dtbOff,
    float* __restrict__ u, float* __restrict__ xdbl, float* __restrict__ dtout){
  __shared__ float us[4*1024];
  __shared__ float part[16*64];
  __shared__ float dtr[4*32];
  int blk = blockIdx.x;
  int dir = blk >> 8, rem = blk & 255, b = rem >> 6, lg = rem & 63;
  int l0 = lg*4;
  const float* cw  = dir ? cwB  : cwF;
  const float* cb  = dir ? cbB  : cbF;
  const float* xw  = dir ? xwB  : xwF;
  const float* dtw = dir ? dtwB : dtwF;
  const float* dtb = dir ? dtbB : dtbF;
  int t = threadIdx.x;
  int rbase = (dir*BB + b)*LL;
  for (int dd = 0; dd < 4; ++dd){
    int d = t + dd*256;
    float4 w4 = *(const float4*)(cw + cwOff + d*4);
    float wf[4] = {w4.x, w4.y, w4.z, w4.w};
    float bias = cb[cbOff + d];
#pragma unroll
    for (int r = 0; r < 4; ++r){
      int l = l0 + r;
      float acc = bias;
#pragma unroll
      for (int k = 0; k < 4; ++k){
        int li = l + k - 3;
        if (li >= 0){
          int sl = dir ? (LL-1-li) : li;
          acc = fmaf(xz[(size_t)(b*LL + sl)*2048 + d], wf[k], acc);
        }
      }
      float uval = silu_f(acc);
      us[r*1024 + d] = uval;
      u[(size_t)(rbase + l)*DI + d] = uval;
    }
  }
  __syncthreads();
  {
    int e = t & 63, pr = t >> 6;
    float accs[4] = {};
    const float* wr = xw + xwOff + (size_t)e*1024 + pr*256;
    for (int i = 0; i < 256; i += 8){
      float4 w0 = *(const float4*)(wr + i);
      float4 w1 = *(const float4*)(wr + i + 4);
      float wf[8] = {w0.x,w0.y,w0.z,w0.w,w1.x,w1.y,w1.z,w1.w};
#pragma unroll
      for (int r = 0; r < 4; ++r){
        const float* ub = us + r*1024 + pr*256 + i;
#pragma unroll
        for (int j = 0; j < 8; ++j)
          accs[r] = fmaf(ub[j], wf[j], accs[r]);
      }
    }
#pragma unroll
    for (int r = 0; r < 4; ++r) part[(pr*4 + r)*64 + e] = accs[r];
  }
  __syncthreads();
  {
    int r = t >> 6, e = t & 63;
    float v = part[(0*4+r)*64+e] + part[(1*4+r)*64+e] +
              part[(2*4+r)*64+e] + part[(3*4+r)*64+e];
    xdbl[(size_t)(rbase + l0 + r)*64 + e] = v;
    if (e < 32) dtr[r*32 + e] = v;
  }
  __syncthreads();
  for (int dd = 0; dd < 4; ++dd){
    int d = t + dd*256;
    float bias = dtb[dtbOff + d];
    float accs[4] = {bias, bias, bias, bias};
    const float* wr = dtw + dtwOff + (size_t)d*32;
    for (int i = 0; i < 32; i += 8){
      float4 w0 = *(const float4*)(wr + i);
      float4 w1 = *(const float4*)(wr + i + 4);
      float wf[8] = {w0.x,w0.y,w0.z,w0.w,w1.x,w1.y,w1.z,w1.w};
#pragma unroll
      for (int r = 0; r < 4; ++r)
#pragma unroll
        for (int j = 0; j < 8; ++j)
          accs[r] = fmaf(dtr[r*32 + i + j], wf[j], accs[r]);
    }
#pragma unroll
    for (int r = 0; r < 4; ++r){
      float sv = accs[r];
      dtout[(size_t)(rbase + l0 + r)*DI + d] = (sv > 15.f) ? sv : log1pf(__expf(sv));
    }
  }
}

// ---- chunked selective scan: block per (dir,b,d); threads (c16, s16) ----
__global__ __launch_bounds__(256) void scan_chunked(const float* __restrict__ dt,
    const float* __restrict__ u, const float* __restrict__ xd,
    const float* __restrict__ AlogF, const float* __restrict__ AlogB,
    const float* __restrict__ DF, const float* __restrict__ DB,
    int aOff, int dOff, float* __restrict__ y){
  __shared__ float cA[16][17], cB[16][17], hin[16][17];
  int blk = blockIdx.x;
  int dir = blk >> 12, rem = blk & 4095, b = rem >> 10, d = rem & 1023;
  int t = threadIdx.x, s = t & 15, c = t >> 4;
  const float* Alog = dir ? AlogB : AlogF;
  const float* Dpt  = dir ? DB : DF;
  float A  = -__expf(Alog[aOff + d*16 + s]);
  float Dp = Dpt[dOff + d];
  int rbase = (dir*BB + b)*LL;
  const float* dtp = dt + (size_t)rbase*DI + d;
  const float* up  = u  + (size_t)rbase*DI + d;
  const float* xr  = xd + (size_t)rbase*64;
  int l0 = c*16;
  float uv[16], ab[16], bb[16];
  {
    float dtv[16], Bv[16];
#pragma unroll
    for (int i = 0; i < 16; ++i){
      dtv[i] = dtp[(size_t)(l0+i)*DI];
      uv[i]  = up[(size_t)(l0+i)*DI];
      Bv[i]  = xr[(l0+i)*64 + 32 + s];
    }
    float Ap = 1.f, hh = 0.f;
#pragma unroll
    for (int i = 0; i < 16; ++i){
      float a  = __expf(dtv[i]*A);
      float bv = dtv[i]*uv[i]*Bv[i];
      ab[i] = a; bb[i] = bv;
      Ap *= a;
      hh = fmaf(a, hh, bv);
    }
    cA[c][s] = Ap; cB[c][s] = hh;
  }
  float Cv[16];
#pragma unroll
  for (int i = 0; i < 16; ++i) Cv[i] = xr[(l0+i)*64 + 48 + s];
  __syncthreads();
  if (t < 16){
    float run = 0.f;
#pragma unroll
    for (int cc = 0; cc < 16; ++cc){
      hin[cc][t] = run;
      run = fmaf(cA[cc][t], run, cB[cc][t]);
    }
  }
  __syncthreads();
  float hh = hin[c][s];
  float* yp = y + (size_t)rbase*DI + d;
#pragma unroll
  for (int i = 0; i < 16; ++i){
    hh = fmaf(ab[i], hh, bb[i]);
    float p = hh * Cv[i];
    p += __shfl_xor(p, 1, 64);
    p += __shfl_xor(p, 2, 64);
    p += __shfl_xor(p, 4, 64);
    p += __shfl_xor(p, 8, 64);
    if (s == 0){
      int l = l0 + i;
      int lo = dir ? (LL-1-l) : l;
      yp[(size_t)lo*DI] = p + uv[i]*Dp;
    }
  }
}

// ---- final LayerNorm (per token row) ----
__global__ __launch_bounds__(256) void ln_kernel(const float* __restrict__ x,
    const float* __restrict__ w, const float* __restrict__ bias,
    float* __restrict__ y){
  __shared__ float sc[8];
  int row = blockIdx.x, t = threadIdx.x;
  const float* xr = x + (size_t)row*DM;
  float v0 = xr[t], v1 = xr[t + 256];
  float s = v0 + v1, ss = v0*v0 + v1*v1;
  block_reduce2(s, ss, sc, 4);
  float mean = s * (1.f/512.f);
  float var = ss * (1.f/512.f) - mean*mean;
  float inv = rsqrtf(var + 1e-5f);
  float* yr = y + (size_t)row*DM;
  yr[t]       = (v0 - mean)*inv*w[t]       + bias[t];
  yr[t + 256] = (v1 - mean)*inv*w[t + 256] + bias[t + 256];
}

// ---- pool (mean over L) + LN + fc1/relu + fc2; block per batch ----
__global__ __launch_bounds__(512) void head_pool(const float* __restrict__ hn,
    const float* __restrict__ lnw, const float* __restrict__ lnb,
    const float* __restrict__ fc1w, const float* __restrict__ fc1b,
    const float* __restrict__ fc2w, const float* __restrict__ fc2b,
    float* __restrict__ out){
  __shared__ float sc[16];
  __shared__ float cbuf[512];
  __shared__ float rbuf[512];
  int b = blockIdx.x, t = threadIdx.x;
  float v = 0.f;
  for (int l = 0; l < 256; ++l) v += hn[(size_t)(b*256 + l)*512 + t];
  v *= (1.f/256.f);
  float s = v, ss = v*v;
  block_reduce2(s, ss, sc, 8);
  float mean = s * (1.f/512.f);
  float var = ss * (1.f/512.f) - mean*mean;
  float inv = rsqrtf(var + 1e-5f);
  cbuf[t] = (v - mean)*inv*lnw[t] + lnb[t];
  __syncthreads();
  float a = fc1b[t];
  const float* w1 = fc1w + (size_t)t*512;
  for (int i = 0; i < 512; i += 8){
    float4 w0 = *(const float4*)(w1 + i);
    float4 w4 = *(const float4*)(w1 + i + 4);
    float wf[8] = {w0.x,w0.y,w0.z,w0.w,w4.x,w4.y,w4.z,w4.w};
#pragma unroll
    for (int j = 0; j < 8; ++j) a = fmaf(cbuf[i + j], wf[j], a);
  }
  rbuf[t] = fmaxf(a, 0.f);
  __syncthreads();
  if (t < 10){
    float a2 = fc2b[t];
    const float* w2 = fc2w + (size_t)t*512;
    for (int i = 0; i < 512; ++i) a2 = fmaf(rbuf[i], w2[i], a2);
    out[b*10 + t] = a2;
  }
}

extern "C" void kernel_launch(void* const* d_in, const int* in_sizes, int n_in,
                              void* d_out, int out_size, void* d_ws, size_t ws_size,
                              hipStream_t stream) {
  (void)in_sizes; (void)n_in; (void)out_size; (void)ws_size;
  const float* x          = (const float*)d_in[0];
  const float* patch_w    = (const float*)d_in[1];
  const float* patch_b    = (const float*)d_in[2];
  const float* in_proj_w  = (const float*)d_in[3];
  const float* conv_w_f   = (const float*)d_in[4];
  const float* conv_b_f   = (const float*)d_in[5];
  const float* xproj_w_f  = (const float*)d_in[6];
  const float* dtproj_w_f = (const float*)d_in[7];
  const float* dtproj_b_f = (const float*)d_in[8];
  const float* A_log_f    = (const float*)d_in[9];
  const float* D_f        = (const float*)d_in[10];
  const float* conv_w_b   = (const float*)d_in[11];
  const float* conv_b_b   = (const float*)d_in[12];
  const float* xproj_w_b  = (const float*)d_in[13];
  const float* dtproj_w_b = (const float*)d_in[14];
  const float* dtproj_b_b = (const float*)d_in[15];
  const float* A_log_b    = (const float*)d_in[16];
  const float* D_b        = (const float*)d_in[17];
  const float* out_proj_w = (const float*)d_in[18];
  const float* norm_w     = (const float*)d_in[19];
  const float* norm_b     = (const float*)d_in[20];
  const float* normf_w    = (const float*)d_in[21];
  const float* normf_b    = (const float*)d_in[22];
  const float* ln_w       = (const float*)d_in[23];
  const float* ln_b       = (const float*)d_in[24];
  const float* fc1_w      = (const float*)d_in[25];
  const float* fc1_b      = (const float*)d_in[26];
  const float* fc2_w      = (const float*)d_in[27];
  const float* fc2_b      = (const float*)d_in[28];

  float* ws   = (float*)d_ws;
  float* hbuf = ws;                 // 524288
  float* xz   = ws + 524288;        // 2097152
  float* ubuf = ws + 2621440;       // 2097152 (2 dirs)
  float* xdbl = ws + 4718592;       // 131072  (2 dirs)
  float* dtb  = ws + 4849664;       // 2097152 (2 dirs)
  float* ybuf = ws + 6946816;       // 2097152 (2 dirs)
  float* hn   = ws + 9043968;       // 524288

  patch_embed<<<128, 256, 0, stream>>>(x, patch_w, patch_b, hbuf);
  for (int i = 0; i < 4; ++i){
    gemm1_ln_mfma<<<dim3(32, 16), 256, 0, stream>>>(
        hbuf, norm_w, norm_b, i*512, in_proj_w, i*1048576, xz);
    fused_cxd<<<512, 256, 0, stream>>>(
        xz, conv_w_f, conv_b_f, conv_w_b, conv_b_b, xproj_w_f, xproj_w_b,
        dtproj_w_f, dtproj_b_f, dtproj_w_b, dtproj_b_b,
        i*4096, i*1024, i*65536, i*32768, i*1024, ubuf, xdbl, dtb);
    scan_chunked<<<8192, 256, 0, stream>>>(
        dtb, ubuf, xdbl, A_log_f, A_log_b, D_f, D_b, i*16384, i*1024, ybuf);
    gemm2_gate_mfma<<<dim3(8, 16), 256, 0, stream>>>(
        ybuf, xz, out_proj_w, i*524288, hbuf);
  }
  ln_kernel<<<1024, 256, 0, stream>>>(hbuf, normf_w, normf_b, hn);
  head_pool<<<4, 512, 0, stream>>>(hn, ln_w, ln_b, fc1_w, fc1_b, fc2_w, fc2_b,
                                   (float*)d_out);
}

// Round 6
// 851.052 us; speedup vs baseline: 1.3144x; 1.3144x over previous
//
#include <hip/hip_runtime.h>

// AudioMamba forward, fp32 activations; big GEMMs via split-bf16 MFMA with
// LDS staging + pre-split weights (hi/lo, 3 MFMAs, fp32-accurate).
// Inputs fp32, output fp32. B=4, L=256, DM=512, DI=1024, S=16, R=32, DEPTH=4.

#define BB 4
#define LL 256
#define DM 512
#define DI 1024

typedef unsigned short u16;
typedef unsigned int u32;
typedef __attribute__((ext_vector_type(8))) short s8v;   // 8 bf16 (4 VGPRs)
typedef __attribute__((ext_vector_type(4))) float f4v;   // MFMA accumulator

__device__ __forceinline__ float silu_f(float x){ return x/(1.f+__expf(-x)); }
__device__ __forceinline__ float b2f(u16 u){
  union { u32 i; float f; } v; v.i = ((u32)u) << 16; return v.f;
}
__device__ __forceinline__ u16 f2bf(float f){
  union { float f; u32 u; } v; v.f = f;
  u32 r = (v.u + 0x7fffu + ((v.u >> 16) & 1u)) >> 16;
  return (u16)r;
}
// split 8 fp32 into hi/lo bf16 fragments (v ~= hi + lo to ~2^-17 rel)
__device__ __forceinline__ void split8(const float* f, s8v& hi, s8v& lo){
#pragma unroll
  for (int j = 0; j < 8; ++j){
    u16 h = f2bf(f[j]);
    float hf = b2f(h);
    hi[j] = (short)h;
    lo[j] = (short)f2bf(f[j] - hf);
  }
}

__device__ __forceinline__ void block_reduce2(float& a, float& b, float* sc, int nw){
  int lane = threadIdx.x & 63, wid = threadIdx.x >> 6;
#pragma unroll
  for (int o = 32; o > 0; o >>= 1){
    a += __shfl_down(a, o, 64);
    b += __shfl_down(b, o, 64);
  }
  if (lane == 0){ sc[wid*2] = a; sc[wid*2+1] = b; }
  __syncthreads();
  float ta = 0.f, tb = 0.f;
  for (int i = 0; i < nw; ++i){ ta += sc[i*2]; tb += sc[i*2+1]; }
  a = ta; b = tb;
}

// ---- per-layer weight split: fp32 -> bf16 hi/lo (in_proj 2048x512, out_proj 512x1024)
__global__ __launch_bounds__(256) void convert_w(const float* __restrict__ inW,
    const float* __restrict__ outW, u16* __restrict__ inHi, u16* __restrict__ inLo,
    u16* __restrict__ outHi, u16* __restrict__ outLo){
  int idx = blockIdx.x*256 + threadIdx.x;
  const float4* src; ushort4* dh; ushort4* dl;
  if (idx < 262144){
    src = (const float4*)inW + idx;
    dh = (ushort4*)inHi + idx; dl = (ushort4*)inLo + idx;
  } else {
    int j = idx - 262144;
    src = (const float4*)outW + j;
    dh = (ushort4*)outHi + j; dl = (ushort4*)outLo + j;
  }
  float4 v = *src;
  ushort4 h, l;
  h.x = f2bf(v.x); l.x = f2bf(v.x - b2f(h.x));
  h.y = f2bf(v.y); l.y = f2bf(v.y - b2f(h.y));
  h.z = f2bf(v.z); l.z = f2bf(v.z - b2f(h.z));
  h.w = f2bf(v.w); l.w = f2bf(v.w - b2f(h.w));
  *dh = h; *dl = l;
}

// ---- patch embed: 128 blocks (b4, ph8, pg4); each block does 8 tokens ----
__global__ __launch_bounds__(256) void patch_embed(const float* __restrict__ x,
    const float* __restrict__ pw, const float* __restrict__ pb, float* __restrict__ h){
  __shared__ float xs[8*256];
  int blk = blockIdx.x;
  int b = blk >> 5, ph = (blk >> 2) & 7, pg = blk & 3;
  int t = threadIdx.x;
  for (int idx = t; idx < 2048; idx += 256){
    int j = idx >> 8, pix = idx & 255, p = pix >> 4, q = pix & 15;
    xs[idx] = x[(size_t)(b*128 + ph*16 + p)*512 + pg*128 + j*16 + q];
  }
  __syncthreads();
  for (int dd = 0; dd < 2; ++dd){
    int d = t + dd*256;
    float acc[8] = {};
    const float* wr = pw + (size_t)d*256;
    for (int i = 0; i < 256; i += 8){
      float4 w0 = *(const float4*)(wr + i);
      float4 w1 = *(const float4*)(wr + i + 4);
      float wf[8] = {w0.x,w0.y,w0.z,w0.w,w1.x,w1.y,w1.z,w1.w};
#pragma unroll
      for (int j = 0; j < 8; ++j){
#pragma unroll
        for (int jj = 0; jj < 8; ++jj)
          acc[j] = fmaf(xs[j*256 + i + jj], wf[jj], acc[j]);
      }
    }
    float bias = pb[d];
#pragma unroll
    for (int j = 0; j < 8; ++j)
      h[(size_t)(b*256 + ph*32 + pg*8 + j)*512 + d] = acc[j] + bias;
  }
}

// ---- in_proj via LDS-staged MFMA, LN fused into A staging ----
// C(1024,2048) = LN(X)(1024,512) @ W(2048,512)^T ; W pre-split bf16 hi/lo
__global__ __launch_bounds__(256) void gemm1_ln_mfma(const float* __restrict__ X,
    const float* __restrict__ lnw, const float* __restrict__ lnb, int lnOff,
    const u16* __restrict__ Whi, const u16* __restrict__ Wlo, float* __restrict__ C){
  __shared__ __align__(16) u16 Ah[2048], Al[2048], Bh[2048], Bl[2048];
  __shared__ float rmean[64], rrstd[64];
  int bm = blockIdx.y*64, bn = blockIdx.x*64;
  int t = threadIdx.x;
  int sr = t >> 2, sc = (t & 3)*8;
  { // LN row stats for the 64 A-rows
    const float* xr = X + (size_t)(bm + sr)*512 + (t & 3)*128;
    float s = 0.f, ss = 0.f;
    for (int i = 0; i < 128; i += 4){
      float4 v = *(const float4*)(xr + i);
      s  += v.x + v.y + v.z + v.w;
      ss += v.x*v.x + v.y*v.y + v.z*v.z + v.w*v.w;
    }
    s += __shfl_xor(s, 1, 64); ss += __shfl_xor(ss, 1, 64);
    s += __shfl_xor(s, 2, 64); ss += __shfl_xor(ss, 2, 64);
    if ((t & 3) == 0){
      float m = s * (1.f/512.f);
      float var = ss * (1.f/512.f) - m*m;
      rmean[sr] = m; rrstd[sr] = rsqrtf(var + 1e-5f);
    }
  }
  __syncthreads();
  float mm = rmean[sr], rr = rrstd[sr];
  int lane = t & 63, wv = t >> 6, ml = lane & 15, quad = lane >> 4;
  int mq = wv >> 1, nq = wv & 1;
  f4v acc[2][2] = {};
  for (int k0 = 0; k0 < 512; k0 += 32){
    // stage A (fp32 -> LN -> split bf16 hi/lo)
    const float* xr = X + (size_t)(bm + sr)*512 + k0 + sc;
    float4 a0 = *(const float4*)xr;
    float4 a1 = *(const float4*)(xr + 4);
    float4 g0 = *(const float4*)(lnw + lnOff + k0 + sc);
    float4 g1 = *(const float4*)(lnw + lnOff + k0 + sc + 4);
    float4 c0 = *(const float4*)(lnb + lnOff + k0 + sc);
    float4 c1 = *(const float4*)(lnb + lnOff + k0 + sc + 4);
    float af[8] = {
      (a0.x-mm)*rr*g0.x + c0.x, (a0.y-mm)*rr*g0.y + c0.y,
      (a0.z-mm)*rr*g0.z + c0.z, (a0.w-mm)*rr*g0.w + c0.w,
      (a1.x-mm)*rr*g1.x + c1.x, (a1.y-mm)*rr*g1.y + c1.y,
      (a1.z-mm)*rr*g1.z + c1.z, (a1.w-mm)*rr*g1.w + c1.w };
    s8v ahv, alv; split8(af, ahv, alv);
    *(s8v*)&Ah[sr*32 + sc] = ahv;
    *(s8v*)&Al[sr*32 + sc] = alv;
    // stage B (pre-split bf16, straight copy)
    uint4 bhv = *(const uint4*)(Whi + (size_t)(bn + sr)*512 + k0 + sc);
    uint4 blv = *(const uint4*)(Wlo + (size_t)(bn + sr)*512 + k0 + sc);
    *(uint4*)&Bh[sr*32 + sc] = bhv;
    *(uint4*)&Bl[sr*32 + sc] = blv;
    __syncthreads();
    s8v ah[2], al2[2], bh2[2], bl2[2];
#pragma unroll
    for (int mt = 0; mt < 2; ++mt){
      int row = mq*32 + mt*16 + ml;
      ah[mt]  = *(s8v*)&Ah[row*32 + quad*8];
      al2[mt] = *(s8v*)&Al[row*32 + quad*8];
    }
#pragma unroll
    for (int nt = 0; nt < 2; ++nt){
      int col = nq*32 + nt*16 + ml;
      bh2[nt] = *(s8v*)&Bh[col*32 + quad*8];
      bl2[nt] = *(s8v*)&Bl[col*32 + quad*8];
    }
#pragma unroll
    for (int mt = 0; mt < 2; ++mt)
#pragma unroll
      for (int nt = 0; nt < 2; ++nt){
        acc[mt][nt] = __builtin_amdgcn_mfma_f32_16x16x32_bf16(ah[mt],  bh2[nt], acc[mt][nt], 0, 0, 0);
        acc[mt][nt] = __builtin_amdgcn_mfma_f32_16x16x32_bf16(al2[mt], bh2[nt], acc[mt][nt], 0, 0, 0);
        acc[mt][nt] = __builtin_amdgcn_mfma_f32_16x16x32_bf16(ah[mt],  bl2[nt], acc[mt][nt], 0, 0, 0);
      }
    __syncthreads();
  }
#pragma unroll
  for (int mt = 0; mt < 2; ++mt)
#pragma unroll
    for (int nt = 0; nt < 2; ++nt)
#pragma unroll
      for (int r = 0; r < 4; ++r)
        C[(size_t)(bm + mq*32 + mt*16 + quad*4 + r)*2048 + bn + nq*32 + nt*16 + ml] =
            acc[mt][nt][r];
}

// ---- out_proj via LDS-staged MFMA, gate fused into A staging, residual += ----
// C(1024,512) += [(yf+yb)*silu(z)](1024,1024) @ W(512,1024)^T
__global__ __launch_bounds__(256) void gemm2_gate_mfma(const float* __restrict__ yb2,
    const float* __restrict__ xz, const u16* __restrict__ Whi,
    const u16* __restrict__ Wlo, float* __restrict__ C){
  __shared__ __align__(16) u16 Ah[2048], Al[2048], Bh[2048], Bl[2048];
  int bm = blockIdx.y*64, bn = blockIdx.x*64;
  int t = threadIdx.x;
  int sr = t >> 2, sc = (t & 3)*8;
  int lane = t & 63, wv = t >> 6, ml = lane & 15, quad = lane >> 4;
  int mq = wv >> 1, nq = wv & 1;
  f4v acc[2][2] = {};
  for (int k0 = 0; k0 < 1024; k0 += 32){
    int m = bm + sr;
    const float* fp = yb2 + (size_t)m*DI + k0 + sc;
    const float* rp = yb2 + (size_t)(1024 + m)*DI + k0 + sc;
    const float* zp = xz + (size_t)m*2048 + 1024 + k0 + sc;
    float4 f0 = *(const float4*)fp,       f1 = *(const float4*)(fp + 4);
    float4 r0 = *(const float4*)rp,       r1 = *(const float4*)(rp + 4);
    float4 z0 = *(const float4*)zp,       z1 = *(const float4*)(zp + 4);
    float af[8] = {
      (f0.x+r0.x)*silu_f(z0.x), (f0.y+r0.y)*silu_f(z0.y),
      (f0.z+r0.z)*silu_f(z0.z), (f0.w+r0.w)*silu_f(z0.w),
      (f1.x+r1.x)*silu_f(z1.x), (f1.y+r1.y)*silu_f(z1.y),
      (f1.z+r1.z)*silu_f(z1.z), (f1.w+r1.w)*silu_f(z1.w) };
    s8v ahv, alv; split8(af, ahv, alv);
    *(s8v*)&Ah[sr*32 + sc] = ahv;
    *(s8v*)&Al[sr*32 + sc] = alv;
    uint4 bhv = *(const uint4*)(Whi + (size_t)(bn + sr)*1024 + k0 + sc);
    uint4 blv = *(const uint4*)(Wlo + (size_t)(bn + sr)*1024 + k0 + sc);
    *(uint4*)&Bh[sr*32 + sc] = bhv;
    *(uint4*)&Bl[sr*32 + sc] = blv;
    __syncthreads();
    s8v ah[2], al2[2], bh2[2], bl2[2];
#pragma unroll
    for (int mt = 0; mt < 2; ++mt){
      int row = mq*32 + mt*16 + ml;
      ah[mt]  = *(s8v*)&Ah[row*32 + quad*8];
      al2[mt] = *(s8v*)&Al[row*32 + quad*8];
    }
#pragma unroll
    for (int nt = 0; nt < 2; ++nt){
      int col = nq*32 + nt*16 + ml;
      bh2[nt] = *(s8v*)&Bh[col*32 + quad*8];
      bl2[nt] = *(s8v*)&Bl[col*32 + quad*8];
    }
#pragma unroll
    for (int mt = 0; mt < 2; ++mt)
#pragma unroll
      for (int nt = 0; nt < 2; ++nt){
        acc[mt][nt] = __builtin_amdgcn_mfma_f32_16x16x32_bf16(ah[mt],  bh2[nt], acc[mt][nt], 0, 0, 0);
        acc[mt][nt] = __builtin_amdgcn_mfma_f32_16x16x32_bf16(al2[mt], bh2[nt], acc[mt][nt], 0, 0, 0);
        acc[mt][nt] = __builtin_amdgcn_mfma_f32_16x16x32_bf16(ah[mt],  bl2[nt], acc[mt][nt], 0, 0, 0);
      }
    __syncthreads();
  }
#pragma unroll
  for (int mt = 0; mt < 2; ++mt)
#pragma unroll
    for (int nt = 0; nt < 2; ++nt)
#pragma unroll
      for (int r = 0; r < 4; ++r){
        float* cp = C + (size_t)(bm + mq*32 + mt*16 + quad*4 + r)*512 +
                    bn + nq*32 + nt*16 + ml;
        *cp += acc[mt][nt][r];
      }
}

// ---- fused conv+silu -> xproj -> dtproj+softplus; block per (dir,b, 4 l's) ----
__global__ __launch_bounds__(256) void fused_cxd(const float* __restrict__ xz,
    const float* __restrict__ cwF, const float* __restrict__ cbF,
    const float* __restrict__ cwB, const float* __restrict__ cbB,
    const float* __restrict__ xwF, const float* __restrict__ xwB,
    const float* __restrict__ dtwF, const float* __restrict__ dtbF,
    const float* __restrict__ dtwB, const float* __restrict__ dtbB,
    int cwOff, int cbOff, int xwOff, int dtwOff, int dtbOff,
    float* __restrict__ u, float* __restrict__ xdbl, float* __restrict__ dtout){
  __shared__ float us[4*1024];
  __shared__ float part[16*64];
  __shared__ float dtr[4*32];
  int blk = blockIdx.x;
  int dir = blk >> 8, rem = blk & 255, b = rem >> 6, lg = rem & 63;
  int l0 = lg*4;
  const float* cw  = dir ? cwB  : cwF;
  const float* cb  = dir ? cbB  : cbF;
  const float* xw  = dir ? xwB  : xwF;
  const float* dtw = dir ? dtwB : dtwF;
  const float* dtb = dir ? dtbB : dtbF;
  int t = threadIdx.x;
  int rbase = (dir*BB + b)*LL;
  for (int dd = 0; dd < 4; ++dd){
    int d = t + dd*256;
    float4 w4 = *(const float4*)(cw + cwOff + d*4);
    float wf[4] = {w4.x, w4.y, w4.z, w4.w};
    float bias = cb[cbOff + d];
#pragma unroll
    for (int r = 0; r < 4; ++r){
      int l = l0 + r;
      float acc = bias;
#pragma unroll
      for (int k = 0; k < 4; ++k){
        int li = l + k - 3;
        if (li >= 0){
          int sl = dir ? (LL-1-li) : li;
          acc = fmaf(xz[(size_t)(b*LL + sl)*2048 + d], wf[k], acc);
        }
      }
      float uval = silu_f(acc);
      us[r*1024 + d] = uval;
      u[(size_t)(rbase + l)*DI + d] = uval;
    }
  }
  __syncthreads();
  {
    int e = t & 63, pr = t >> 6;
    float accs[4] = {};
    const float* wr = xw + xwOff + (size_t)e*1024 + pr*256;
    for (int i = 0; i < 256; i += 8){
      float4 w0 = *(const float4*)(wr + i);
      float4 w1 = *(const float4*)(wr + i + 4);
      float wf[8] = {w0.x,w0.y,w0.z,w0.w,w1.x,w1.y,w1.z,w1.w};
#pragma unroll
      for (int r = 0; r < 4; ++r){
        const float* ub = us + r*1024 + pr*256 + i;
#pragma unroll
        for (int j = 0; j < 8; ++j)
          accs[r] = fmaf(ub[j], wf[j], accs[r]);
      }
    }
#pragma unroll
    for (int r = 0; r < 4; ++r) part[(pr*4 + r)*64 + e] = accs[r];
  }
  __syncthreads();
  {
    int r = t >> 6, e = t & 63;
    float v = part[(0*4+r)*64+e] + part[(1*4+r)*64+e] +
              part[(2*4+r)*64+e] + part[(3*4+r)*64+e];
    xdbl[(size_t)(rbase + l0 + r)*64 + e] = v;
    if (e < 32) dtr[r*32 + e] = v;
  }
  __syncthreads();
  for (int dd = 0; dd < 4; ++dd){
    int d = t + dd*256;
    float bias = dtb[dtbOff + d];
    float accs[4] = {bias, bias, bias, bias};
    const float* wr = dtw + dtwOff + (size_t)d*32;
    for (int i = 0; i < 32; i += 8){
      float4 w0 = *(const float4*)(wr + i);
      float4 w1 = *(const float4*)(wr + i + 4);
      float wf[8] = {w0.x,w0.y,w0.z,w0.w,w1.x,w1.y,w1.z,w1.w};
#pragma unroll
      for (int r = 0; r < 4; ++r)
#pragma unroll
        for (int j = 0; j < 8; ++j)
          accs[r] = fmaf(dtr[r*32 + i + j], wf[j], accs[r]);
    }
#pragma unroll
    for (int r = 0; r < 4; ++r){
      float sv = accs[r];
      dtout[(size_t)(rbase + l0 + r)*DI + d] = (sv > 15.f) ? sv : log1pf(__expf(sv));
    }
  }
}

// ---- chunked selective scan: block per (dir,b,d); threads (c16, s16) ----
__global__ __launch_bounds__(256) void scan_chunked(const float* __restrict__ dt,
    const float* __restrict__ u, const float* __restrict__ xd,
    const float* __restrict__ AlogF, const float* __restrict__ AlogB,
    const float* __restrict__ DF, const float* __restrict__ DB,
    int aOff, int dOff, float* __restrict__ y){
  __shared__ float cA[16][17], cB[16][17], hin[16][17];
  int blk = blockIdx.x;
  int dir = blk >> 12, rem = blk & 4095, b = rem >> 10, d = rem & 1023;
  int t = threadIdx.x, s = t & 15, c = t >> 4;
  const float* Alog = dir ? AlogB : AlogF;
  const float* Dpt  = dir ? DB : DF;
  float A  = -__expf(Alog[aOff + d*16 + s]);
  float Dp = Dpt[dOff + d];
  int rbase = (dir*BB + b)*LL;
  const float* dtp = dt + (size_t)rbase*DI + d;
  const float* up  = u  + (size_t)rbase*DI + d;
  const float* xr  = xd + (size_t)rbase*64;
  int l0 = c*16;
  float uv[16], ab[16], bb[16];
  {
    float dtv[16], Bv[16];
#pragma unroll
    for (int i = 0; i < 16; ++i){
      dtv[i] = dtp[(size_t)(l0+i)*DI];
      uv[i]  = up[(size_t)(l0+i)*DI];
      Bv[i]  = xr[(l0+i)*64 + 32 + s];
    }
    float Ap = 1.f, hh = 0.f;
#pragma unroll
    for (int i = 0; i < 16; ++i){
      float a  = __expf(dtv[i]*A);
      float bv = dtv[i]*uv[i]*Bv[i];
      ab[i] = a; bb[i] = bv;
      Ap *= a;
      hh = fmaf(a, hh, bv);
    }
    cA[c][s] = Ap; cB[c][s] = hh;
  }
  float Cv[16];
#pragma unroll
  for (int i = 0; i < 16; ++i) Cv[i] = xr[(l0+i)*64 + 48 + s];
  __syncthreads();
  if (t < 16){
    float run = 0.f;
#pragma unroll
    for (int cc = 0; cc < 16; ++cc){
      hin[cc][t] = run;
      run = fmaf(cA[cc][t], run, cB[cc][t]);
    }
  }
  __syncthreads();
  float hh = hin[c][s];
  float* yp = y + (size_t)rbase*DI + d;
#pragma unroll
  for (int i = 0; i < 16; ++i){
    hh = fmaf(ab[i], hh, bb[i]);
    float p = hh * Cv[i];
    p += __shfl_xor(p, 1, 64);
    p += __shfl_xor(p, 2, 64);
    p += __shfl_xor(p, 4, 64);
    p += __shfl_xor(p, 8, 64);
    if (s == 0){
      int l = l0 + i;
      int lo = dir ? (LL-1-l) : l;
      yp[(size_t)lo*DI] = p + uv[i]*Dp;
    }
  }
}

// ---- final LayerNorm (per token row) ----
__global__ __launch_bounds__(256) void ln_kernel(const float* __restrict__ x,
    const float* __restrict__ w, const float* __restrict__ bias,
    float* __restrict__ y){
  __shared__ float sc[8];
  int row = blockIdx.x, t = threadIdx.x;
  const float* xr = x + (size_t)row*DM;
  float v0 = xr[t], v1 = xr[t + 256];
  float s = v0 + v1, ss = v0*v0 + v1*v1;
  block_reduce2(s, ss, sc, 4);
  float mean = s * (1.f/512.f);
  float var = ss * (1.f/512.f) - mean*mean;
  float inv = rsqrtf(var + 1e-5f);
  float* yr = y + (size_t)row*DM;
  yr[t]       = (v0 - mean)*inv*w[t]       + bias[t];
  yr[t + 256] = (v1 - mean)*inv*w[t + 256] + bias[t + 256];
}

// ---- pool (mean over L) + LN + fc1/relu + fc2; block per batch ----
__global__ __launch_bounds__(512) void head_pool(const float* __restrict__ hn,
    const float* __restrict__ lnw, const float* __restrict__ lnb,
    const float* __restrict__ fc1w, const float* __restrict__ fc1b,
    const float* __restrict__ fc2w, const float* __restrict__ fc2b,
    float* __restrict__ out){
  __shared__ float sc[16];
  __shared__ float cbuf[512];
  __shared__ float rbuf[512];
  int b = blockIdx.x, t = threadIdx.x;
  float v = 0.f;
  for (int l = 0; l < 256; ++l) v += hn[(size_t)(b*256 + l)*512 + t];
  v *= (1.f/256.f);
  float s = v, ss = v*v;
  block_reduce2(s, ss, sc, 8);
  float mean = s * (1.f/512.f);
  float var = ss * (1.f/512.f) - mean*mean;
  float inv = rsqrtf(var + 1e-5f);
  cbuf[t] = (v - mean)*inv*lnw[t] + lnb[t];
  __syncthreads();
  float a = fc1b[t];
  const float* w1 = fc1w + (size_t)t*512;
  for (int i = 0; i < 512; i += 8){
    float4 w0 = *(const float4*)(w1 + i);
    float4 w4 = *(const float4*)(w1 + i + 4);
    float wf[8] = {w0.x,w0.y,w0.z,w0.w,w4.x,w4.y,w4.z,w4.w};
#pragma unroll
    for (int j = 0; j < 8; ++j) a = fmaf(cbuf[i + j], wf[j], a);
  }
  rbuf[t] = fmaxf(a, 0.f);
  __syncthreads();
  if (t < 10){
    float a2 = fc2b[t];
    const float* w2 = fc2w + (size_t)t*512;
    for (int i = 0; i < 512; ++i) a2 = fmaf(rbuf[i], w2[i], a2);
    out[b*10 + t] = a2;
  }
}

extern "C" void kernel_launch(void* const* d_in, const int* in_sizes, int n_in,
                              void* d_out, int out_size, void* d_ws, size_t ws_size,
                              hipStream_t stream) {
  (void)in_sizes; (void)n_in; (void)out_size; (void)ws_size;
  const float* x          = (const float*)d_in[0];
  const float* patch_w    = (const float*)d_in[1];
  const float* patch_b    = (const float*)d_in[2];
  const float* in_proj_w  = (const float*)d_in[3];
  const float* conv_w_f   = (const float*)d_in[4];
  const float* conv_b_f   = (const float*)d_in[5];
  const float* xproj_w_f  = (const float*)d_in[6];
  const float* dtproj_w_f = (const float*)d_in[7];
  const float* dtproj_b_f = (const float*)d_in[8];
  const float* A_log_f    = (const float*)d_in[9];
  const float* D_f        = (const float*)d_in[10];
  const float* conv_w_b   = (const float*)d_in[11];
  const float* conv_b_b   = (const float*)d_in[12];
  const float* xproj_w_b  = (const float*)d_in[13];
  const float* dtproj_w_b = (const float*)d_in[14];
  const float* dtproj_b_b = (const float*)d_in[15];
  const float* A_log_b    = (const float*)d_in[16];
  const float* D_b        = (const float*)d_in[17];
  const float* out_proj_w = (const float*)d_in[18];
  const float* norm_w     = (const float*)d_in[19];
  const float* norm_b     = (const float*)d_in[20];
  const float* normf_w    = (const float*)d_in[21];
  const float* normf_b    = (const float*)d_in[22];
  const float* ln_w       = (const float*)d_in[23];
  const float* ln_b       = (const float*)d_in[24];
  const float* fc1_w      = (const float*)d_in[25];
  const float* fc1_b      = (const float*)d_in[26];
  const float* fc2_w      = (const float*)d_in[27];
  const float* fc2_b      = (const float*)d_in[28];

  float* ws   = (float*)d_ws;
  float* hbuf = ws;                 // 524288
  float* xz   = ws + 524288;        // 2097152
  float* ubuf = ws + 2621440;       // 2097152 (2 dirs)
  float* xdbl = ws + 4718592;       // 131072  (2 dirs)
  float* dtb  = ws + 4849664;       // 2097152 (2 dirs)
  float* ybuf = ws + 6946816;       // 2097152 (2 dirs)
  float* hn   = ws + 9043968;       // 524288
  u16*   inHi = (u16*)(ws + 9568256);   // 1048576 u16
  u16*   inLo = (u16*)(ws + 10092544);  // 1048576 u16
  u16*   outHi= (u16*)(ws + 10616832);  // 524288 u16
  u16*   outLo= (u16*)(ws + 10878976);  // 524288 u16

  patch_embed<<<128, 256, 0, stream>>>(x, patch_w, patch_b, hbuf);
  for (int i = 0; i < 4; ++i){
    convert_w<<<1536, 256, 0, stream>>>(in_proj_w + (size_t)i*1048576,
                                        out_proj_w + (size_t)i*524288,
                                        inHi, inLo, outHi, outLo);
    gemm1_ln_mfma<<<dim3(32, 16), 256, 0, stream>>>(
        hbuf, norm_w, norm_b, i*512, inHi, inLo, xz);
    fused_cxd<<<512, 256, 0, stream>>>(
        xz, conv_w_f, conv_b_f, conv_w_b, conv_b_b, xproj_w_f, xproj_w_b,
        dtproj_w_f, dtproj_b_f, dtproj_w_b, dtproj_b_b,
        i*4096, i*1024, i*65536, i*32768, i*1024, ubuf, xdbl, dtb);
    scan_chunked<<<8192, 256, 0, stream>>>(
        dtb, ubuf, xdbl, A_log_f, A_log_b, D_f, D_b, i*16384, i*1024, ybuf);
    gemm2_gate_mfma<<<dim3(8, 16), 256, 0, stream>>>(
        ybuf, xz, outHi, outLo, hbuf);
  }
  ln_kernel<<<1024, 256, 0, stream>>>(hbuf, normf_w, normf_b, hn);
  head_pool<<<4, 512, 0, stream>>>(hn, ln_w, ln_b, fc1_w, fc1_b, fc2_w, fc2_b,
                                   (float*)d_out);
}

// Round 7
// 759.468 us; speedup vs baseline: 1.4729x; 1.1206x over previous
//
#include <hip/hip_runtime.h>

// AudioMamba forward, fp32 activations; big GEMMs via split-bf16 MFMA with
// LDS staging + pre-split weights. Scan: coalesced LDS-tiled chunk scan with
// DPP row reductions. Inputs fp32, output fp32.
// B=4, L=256, DM=512, DI=1024, S=16, R=32, DEPTH=4.

#define BB 4
#define LL 256
#define DM 512
#define DI 1024

typedef unsigned short u16;
typedef unsigned int u32;
typedef __attribute__((ext_vector_type(8))) short s8v;   // 8 bf16 (4 VGPRs)
typedef __attribute__((ext_vector_type(4))) float f4v;   // MFMA accumulator

__device__ __forceinline__ float silu_f(float x){ return x/(1.f+__expf(-x)); }
__device__ __forceinline__ float b2f(u16 u){
  union { u32 i; float f; } v; v.i = ((u32)u) << 16; return v.f;
}
__device__ __forceinline__ u16 f2bf(float f){
  union { float f; u32 u; } v; v.f = f;
  u32 r = (v.u + 0x7fffu + ((v.u >> 16) & 1u)) >> 16;
  return (u16)r;
}
__device__ __forceinline__ void split8(const float* f, s8v& hi, s8v& lo){
#pragma unroll
  for (int j = 0; j < 8; ++j){
    u16 h = f2bf(f[j]);
    float hf = b2f(h);
    hi[j] = (short)h;
    lo[j] = (short)f2bf(f[j] - hf);
  }
}

// sum over 16-lane DPP row; full sum lands in lane 15 of each row (VALU-only)
__device__ __forceinline__ float row_sum16(float p){
  union { float f; int i; } v, r;
  v.f = p;
  r.i = __builtin_amdgcn_update_dpp(0, v.i, 0x111, 0xF, 0xF, true); v.f += r.f;
  r.i = __builtin_amdgcn_update_dpp(0, v.i, 0x112, 0xF, 0xF, true); v.f += r.f;
  r.i = __builtin_amdgcn_update_dpp(0, v.i, 0x114, 0xF, 0xF, true); v.f += r.f;
  r.i = __builtin_amdgcn_update_dpp(0, v.i, 0x118, 0xF, 0xF, true); v.f += r.f;
  return v.f;
}

__device__ __forceinline__ void block_reduce2(float& a, float& b, float* sc, int nw){
  int lane = threadIdx.x & 63, wid = threadIdx.x >> 6;
#pragma unroll
  for (int o = 32; o > 0; o >>= 1){
    a += __shfl_down(a, o, 64);
    b += __shfl_down(b, o, 64);
  }
  if (lane == 0){ sc[wid*2] = a; sc[wid*2+1] = b; }
  __syncthreads();
  float ta = 0.f, tb = 0.f;
  for (int i = 0; i < nw; ++i){ ta += sc[i*2]; tb += sc[i*2+1]; }
  a = ta; b = tb;
}

// ---- per-layer weight split ----
__global__ __launch_bounds__(256) void convert_w(const float* __restrict__ inW,
    const float* __restrict__ outW, u16* __restrict__ inHi, u16* __restrict__ inLo,
    u16* __restrict__ outHi, u16* __restrict__ outLo){
  int idx = blockIdx.x*256 + threadIdx.x;
  const float4* src; ushort4* dh; ushort4* dl;
  if (idx < 262144){
    src = (const float4*)inW + idx;
    dh = (ushort4*)inHi + idx; dl = (ushort4*)inLo + idx;
  } else {
    int j = idx - 262144;
    src = (const float4*)outW + j;
    dh = (ushort4*)outHi + j; dl = (ushort4*)outLo + j;
  }
  float4 v = *src;
  ushort4 h, l;
  h.x = f2bf(v.x); l.x = f2bf(v.x - b2f(h.x));
  h.y = f2bf(v.y); l.y = f2bf(v.y - b2f(h.y));
  h.z = f2bf(v.z); l.z = f2bf(v.z - b2f(h.z));
  h.w = f2bf(v.w); l.w = f2bf(v.w - b2f(h.w));
  *dh = h; *dl = l;
}

// ---- patch embed: 256 blocks (b4, ph8, pg4, dhalf2); 8 tokens per block ----
__global__ __launch_bounds__(256) void patch_embed(const float* __restrict__ x,
    const float* __restrict__ pw, const float* __restrict__ pb, float* __restrict__ h){
  __shared__ float xs[8*256];
  int blk = blockIdx.x;
  int b = blk >> 6, ph = (blk >> 3) & 7, pg = (blk >> 1) & 3, dh = blk & 1;
  int t = threadIdx.x;
  for (int idx = t; idx < 2048; idx += 256){
    int j = idx >> 8, pix = idx & 255, p = pix >> 4, q = pix & 15;
    xs[idx] = x[(size_t)(b*128 + ph*16 + p)*512 + pg*128 + j*16 + q];
  }
  __syncthreads();
  int d = dh*256 + t;
  float acc[8] = {};
  const float* wr = pw + (size_t)d*256;
  for (int i = 0; i < 256; i += 8){
    float4 w0 = *(const float4*)(wr + i);
    float4 w1 = *(const float4*)(wr + i + 4);
    float wf[8] = {w0.x,w0.y,w0.z,w0.w,w1.x,w1.y,w1.z,w1.w};
#pragma unroll
    for (int j = 0; j < 8; ++j){
#pragma unroll
      for (int jj = 0; jj < 8; ++jj)
        acc[j] = fmaf(xs[j*256 + i + jj], wf[jj], acc[j]);
    }
  }
  float bias = pb[d];
#pragma unroll
  for (int j = 0; j < 8; ++j)
    h[(size_t)(b*256 + ph*32 + pg*8 + j)*512 + d] = acc[j] + bias;
}

// ---- in_proj via LDS-staged MFMA, LN fused into A staging ----
__global__ __launch_bounds__(256) void gemm1_ln_mfma(const float* __restrict__ X,
    const float* __restrict__ lnw, const float* __restrict__ lnb, int lnOff,
    const u16* __restrict__ Whi, const u16* __restrict__ Wlo, float* __restrict__ C){
  __shared__ __align__(16) u16 Ah[2048], Al[2048], Bh[2048], Bl[2048];
  __shared__ float rmean[64], rrstd[64];
  int bm = blockIdx.y*64, bn = blockIdx.x*64;
  int t = threadIdx.x;
  int sr = t >> 2, sc = (t & 3)*8;
  {
    const float* xr = X + (size_t)(bm + sr)*512 + (t & 3)*128;
    float s = 0.f, ss = 0.f;
    for (int i = 0; i < 128; i += 4){
      float4 v = *(const float4*)(xr + i);
      s  += v.x + v.y + v.z + v.w;
      ss += v.x*v.x + v.y*v.y + v.z*v.z + v.w*v.w;
    }
    s += __shfl_xor(s, 1, 64); ss += __shfl_xor(ss, 1, 64);
    s += __shfl_xor(s, 2, 64); ss += __shfl_xor(ss, 2, 64);
    if ((t & 3) == 0){
      float m = s * (1.f/512.f);
      float var = ss * (1.f/512.f) - m*m;
      rmean[sr] = m; rrstd[sr] = rsqrtf(var + 1e-5f);
    }
  }
  __syncthreads();
  float mm = rmean[sr], rr = rrstd[sr];
  int lane = t & 63, wv = t >> 6, ml = lane & 15, quad = lane >> 4;
  int mq = wv >> 1, nq = wv & 1;
  f4v acc[2][2] = {};
  for (int k0 = 0; k0 < 512; k0 += 32){
    const float* xr = X + (size_t)(bm + sr)*512 + k0 + sc;
    float4 a0 = *(const float4*)xr;
    float4 a1 = *(const float4*)(xr + 4);
    float4 g0 = *(const float4*)(lnw + lnOff + k0 + sc);
    float4 g1 = *(const float4*)(lnw + lnOff + k0 + sc + 4);
    float4 c0 = *(const float4*)(lnb + lnOff + k0 + sc);
    float4 c1 = *(const float4*)(lnb + lnOff + k0 + sc + 4);
    float af[8] = {
      (a0.x-mm)*rr*g0.x + c0.x, (a0.y-mm)*rr*g0.y + c0.y,
      (a0.z-mm)*rr*g0.z + c0.z, (a0.w-mm)*rr*g0.w + c0.w,
      (a1.x-mm)*rr*g1.x + c1.x, (a1.y-mm)*rr*g1.y + c1.y,
      (a1.z-mm)*rr*g1.z + c1.z, (a1.w-mm)*rr*g1.w + c1.w };
    s8v ahv, alv; split8(af, ahv, alv);
    *(s8v*)&Ah[sr*32 + sc] = ahv;
    *(s8v*)&Al[sr*32 + sc] = alv;
    uint4 bhv = *(const uint4*)(Whi + (size_t)(bn + sr)*512 + k0 + sc);
    uint4 blv = *(const uint4*)(Wlo + (size_t)(bn + sr)*512 + k0 + sc);
    *(uint4*)&Bh[sr*32 + sc] = bhv;
    *(uint4*)&Bl[sr*32 + sc] = blv;
    __syncthreads();
    s8v ah[2], al2[2], bh2[2], bl2[2];
#pragma unroll
    for (int mt = 0; mt < 2; ++mt){
      int row = mq*32 + mt*16 + ml;
      ah[mt]  = *(s8v*)&Ah[row*32 + quad*8];
      al2[mt] = *(s8v*)&Al[row*32 + quad*8];
    }
#pragma unroll
    for (int nt = 0; nt < 2; ++nt){
      int col = nq*32 + nt*16 + ml;
      bh2[nt] = *(s8v*)&Bh[col*32 + quad*8];
      bl2[nt] = *(s8v*)&Bl[col*32 + quad*8];
    }
#pragma unroll
    for (int mt = 0; mt < 2; ++mt)
#pragma unroll
      for (int nt = 0; nt < 2; ++nt){
        acc[mt][nt] = __builtin_amdgcn_mfma_f32_16x16x32_bf16(ah[mt],  bh2[nt], acc[mt][nt], 0, 0, 0);
        acc[mt][nt] = __builtin_amdgcn_mfma_f32_16x16x32_bf16(al2[mt], bh2[nt], acc[mt][nt], 0, 0, 0);
        acc[mt][nt] = __builtin_amdgcn_mfma_f32_16x16x32_bf16(ah[mt],  bl2[nt], acc[mt][nt], 0, 0, 0);
      }
    __syncthreads();
  }
#pragma unroll
  for (int mt = 0; mt < 2; ++mt)
#pragma unroll
    for (int nt = 0; nt < 2; ++nt)
#pragma unroll
      for (int r = 0; r < 4; ++r)
        C[(size_t)(bm + mq*32 + mt*16 + quad*4 + r)*2048 + bn + nq*32 + nt*16 + ml] =
            acc[mt][nt][r];
}

// ---- out_proj via LDS-staged MFMA, gate fused, residual += ----
__global__ __launch_bounds__(256) void gemm2_gate_mfma(const float* __restrict__ yb2,
    const float* __restrict__ xz, const u16* __restrict__ Whi,
    const u16* __restrict__ Wlo, float* __restrict__ C){
  __shared__ __align__(16) u16 Ah[2048], Al[2048], Bh[2048], Bl[2048];
  int bm = blockIdx.y*64, bn = blockIdx.x*64;
  int t = threadIdx.x;
  int sr = t >> 2, sc = (t & 3)*8;
  int lane = t & 63, wv = t >> 6, ml = lane & 15, quad = lane >> 4;
  int mq = wv >> 1, nq = wv & 1;
  f4v acc[2][2] = {};
  for (int k0 = 0; k0 < 1024; k0 += 32){
    int m = bm + sr;
    const float* fp = yb2 + (size_t)m*DI + k0 + sc;
    const float* rp = yb2 + (size_t)(1024 + m)*DI + k0 + sc;
    const float* zp = xz + (size_t)m*2048 + 1024 + k0 + sc;
    float4 f0 = *(const float4*)fp,       f1 = *(const float4*)(fp + 4);
    float4 r0 = *(const float4*)rp,       r1 = *(const float4*)(rp + 4);
    float4 z0 = *(const float4*)zp,       z1 = *(const float4*)(zp + 4);
    float af[8] = {
      (f0.x+r0.x)*silu_f(z0.x), (f0.y+r0.y)*silu_f(z0.y),
      (f0.z+r0.z)*silu_f(z0.z), (f0.w+r0.w)*silu_f(z0.w),
      (f1.x+r1.x)*silu_f(z1.x), (f1.y+r1.y)*silu_f(z1.y),
      (f1.z+r1.z)*silu_f(z1.z), (f1.w+r1.w)*silu_f(z1.w) };
    s8v ahv, alv; split8(af, ahv, alv);
    *(s8v*)&Ah[sr*32 + sc] = ahv;
    *(s8v*)&Al[sr*32 + sc] = alv;
    uint4 bhv = *(const uint4*)(Whi + (size_t)(bn + sr)*1024 + k0 + sc);
    uint4 blv = *(const uint4*)(Wlo + (size_t)(bn + sr)*1024 + k0 + sc);
    *(uint4*)&Bh[sr*32 + sc] = bhv;
    *(uint4*)&Bl[sr*32 + sc] = blv;
    __syncthreads();
    s8v ah[2], al2[2], bh2[2], bl2[2];
#pragma unroll
    for (int mt = 0; mt < 2; ++mt){
      int row = mq*32 + mt*16 + ml;
      ah[mt]  = *(s8v*)&Ah[row*32 + quad*8];
      al2[mt] = *(s8v*)&Al[row*32 + quad*8];
    }
#pragma unroll
    for (int nt = 0; nt < 2; ++nt){
      int col = nq*32 + nt*16 + ml;
      bh2[nt] = *(s8v*)&Bh[col*32 + quad*8];
      bl2[nt] = *(s8v*)&Bl[col*32 + quad*8];
    }
#pragma unroll
    for (int mt = 0; mt < 2; ++mt)
#pragma unroll
      for (int nt = 0; nt < 2; ++nt){
        acc[mt][nt] = __builtin_amdgcn_mfma_f32_16x16x32_bf16(ah[mt],  bh2[nt], acc[mt][nt], 0, 0, 0);
        acc[mt][nt] = __builtin_amdgcn_mfma_f32_16x16x32_bf16(al2[mt], bh2[nt], acc[mt][nt], 0, 0, 0);
        acc[mt][nt] = __builtin_amdgcn_mfma_f32_16x16x32_bf16(ah[mt],  bl2[nt], acc[mt][nt], 0, 0, 0);
      }
    __syncthreads();
  }
#pragma unroll
  for (int mt = 0; mt < 2; ++mt)
#pragma unroll
    for (int nt = 0; nt < 2; ++nt)
#pragma unroll
      for (int r = 0; r < 4; ++r){
        float* cp = C + (size_t)(bm + mq*32 + mt*16 + quad*4 + r)*512 +
                    bn + nq*32 + nt*16 + ml;
        *cp += acc[mt][nt][r];
      }
}

// ---- fused conv+silu -> xproj -> dtproj+softplus; block per (dir,b, 4 l's) ----
__global__ __launch_bounds__(256) void fused_cxd(const float* __restrict__ xz,
    const float* __restrict__ cwF, const float* __restrict__ cbF,
    const float* __restrict__ cwB, const float* __restrict__ cbB,
    const float* __restrict__ xwF, const float* __restrict__ xwB,
    const float* __restrict__ dtwF, const float* __restrict__ dtbF,
    const float* __restrict__ dtwB, const float* __restrict__ dtbB,
    int cwOff, int cbOff, int xwOff, int dtwOff, int dtbOff,
    float* __restrict__ u, float* __restrict__ xdbl, float* __restrict__ dtout){
  __shared__ float us[4*1024];
  __shared__ float part[16*64];
  __shared__ float dtr[4*32];
  int blk = blockIdx.x;
  int dir = blk >> 8, rem = blk & 255, b = rem >> 6, lg = rem & 63;
  int l0 = lg*4;
  const float* cw  = dir ? cwB  : cwF;
  const float* cb  = dir ? cbB  : cbF;
  const float* xw  = dir ? xwB  : xwF;
  const float* dtw = dir ? dtwB : dtwF;
  const float* dtb = dir ? dtbB : dtbF;
  int t = threadIdx.x;
  int rbase = (dir*BB + b)*LL;
  for (int dd = 0; dd < 4; ++dd){
    int d = t + dd*256;
    float4 w4 = *(const float4*)(cw + cwOff + d*4);
    float wf[4] = {w4.x, w4.y, w4.z, w4.w};
    float bias = cb[cbOff + d];
#pragma unroll
    for (int r = 0; r < 4; ++r){
      int l = l0 + r;
      float acc = bias;
#pragma unroll
      for (int k = 0; k < 4; ++k){
        int li = l + k - 3;
        if (li >= 0){
          int sl = dir ? (LL-1-li) : li;
          acc = fmaf(xz[(size_t)(b*LL + sl)*2048 + d], wf[k], acc);
        }
      }
      float uval = silu_f(acc);
      us[r*1024 + d] = uval;
      u[(size_t)(rbase + l)*DI + d] = uval;
    }
  }
  __syncthreads();
  {
    int e = t & 63, pr = t >> 6;
    float accs[4] = {};
    const float* wr = xw + xwOff + (size_t)e*1024 + pr*256;
    for (int i = 0; i < 256; i += 8){
      float4 w0 = *(const float4*)(wr + i);
      float4 w1 = *(const float4*)(wr + i + 4);
      float wf[8] = {w0.x,w0.y,w0.z,w0.w,w1.x,w1.y,w1.z,w1.w};
#pragma unroll
      for (int r = 0; r < 4; ++r){
        const float* ub = us + r*1024 + pr*256 + i;
#pragma unroll
        for (int j = 0; j < 8; ++j)
          accs[r] = fmaf(ub[j], wf[j], accs[r]);
      }
    }
#pragma unroll
    for (int r = 0; r < 4; ++r) part[(pr*4 + r)*64 + e] = accs[r];
  }
  __syncthreads();
  {
    int r = t >> 6, e = t & 63;
    float v = part[(0*4+r)*64+e] + part[(1*4+r)*64+e] +
              part[(2*4+r)*64+e] + part[(3*4+r)*64+e];
    xdbl[(size_t)(rbase + l0 + r)*64 + e] = v;
    if (e < 32) dtr[r*32 + e] = v;
  }
  __syncthreads();
  for (int dd = 0; dd < 4; ++dd){
    int d = t + dd*256;
    float bias = dtb[dtbOff + d];
    float accs[4] = {bias, bias, bias, bias};
    const float* wr = dtw + dtwOff + (size_t)d*32;
    for (int i = 0; i < 32; i += 8){
      float4 w0 = *(const float4*)(wr + i);
      float4 w1 = *(const float4*)(wr + i + 4);
      float wf[8] = {w0.x,w0.y,w0.z,w0.w,w1.x,w1.y,w1.z,w1.w};
#pragma unroll
      for (int r = 0; r < 4; ++r)
#pragma unroll
        for (int j = 0; j < 8; ++j)
          accs[r] = fmaf(dtr[r*32 + i + j], wf[j], accs[r]);
    }
#pragma unroll
    for (int r = 0; r < 4; ++r){
      float sv = accs[r];
      dtout[(size_t)(rbase + l0 + r)*DI + d] = (sv > 15.f) ? sv : log1pf(__expf(sv));
    }
  }
}

// ---- coalesced LDS-tiled selective scan ----
// block = (dir, b, 16-d group); thread = (d local, s); 512 blocks.
__global__ __launch_bounds__(256) void scan_coal(const float* __restrict__ dt,
    const float* __restrict__ u, const float* __restrict__ xd,
    const float* __restrict__ AlogF, const float* __restrict__ AlogB,
    const float* __restrict__ DF, const float* __restrict__ DB,
    int aOff, int dOff, float* __restrict__ y){
  __shared__ __align__(16) float dtuT[16][516];  // [d][(dt,u) per l], pad rows
  __shared__ __align__(16) float BCT[16][516];   // [s][(B,C) per l]
  __shared__ __align__(16) float ytile[128][16];
  int blk = blockIdx.x;
  int dir = blk >> 8, b = (blk >> 6) & 3, dg = blk & 63;
  int t = threadIdx.x;
  int rbase = (dir*BB + b)*LL;
  const float* Alog = dir ? AlogB : AlogF;
  const float* Dpt  = dir ? DB : DF;
  // --- stage dt/u: coalesced 64B rows ---
  {
    int q = t & 3, lb = t >> 2;
    for (int pass = 0; pass < 4; ++pass){
      int l = pass*64 + lb;
      float4 dv = *(const float4*)(dt + (size_t)(rbase + l)*DI + dg*16 + q*4);
      float4 uv = *(const float4*)(u  + (size_t)(rbase + l)*DI + dg*16 + q*4);
      float2 p0 = {dv.x, uv.x}, p1 = {dv.y, uv.y}, p2 = {dv.z, uv.z}, p3 = {dv.w, uv.w};
      *(float2*)&dtuT[q*4+0][l*2] = p0;
      *(float2*)&dtuT[q*4+1][l*2] = p1;
      *(float2*)&dtuT[q*4+2][l*2] = p2;
      *(float2*)&dtuT[q*4+3][l*2] = p3;
    }
  }
  // --- stage B/C: xdbl[row][32..63] = B(16) C(16), 128B contiguous ---
  {
    int h8 = t & 7, lb = t >> 3;
    for (int pass = 0; pass < 8; ++pass){
      int l = pass*32 + lb;
      float4 v = *(const float4*)(xd + (size_t)(rbase + l)*64 + 32 + h8*4);
      if (h8 < 4){
        int s0 = h8*4;
        BCT[s0+0][l*2] = v.x; BCT[s0+1][l*2] = v.y;
        BCT[s0+2][l*2] = v.z; BCT[s0+3][l*2] = v.w;
      } else {
        int s0 = (h8-4)*4;
        BCT[s0+0][l*2+1] = v.x; BCT[s0+1][l*2+1] = v.y;
        BCT[s0+2][l*2+1] = v.z; BCT[s0+3][l*2+1] = v.w;
      }
    }
  }
  int s = t & 15, dl = t >> 4;
  float Av = -__expf(Alog[aOff + dg*256 + t]);   // (dg*16+dl)*16+s == dg*256+t
  float Dp = Dpt[dOff + dg*16 + dl];
  __syncthreads();
  float h = 0.f;
  for (int half = 0; half < 2; ++half){
    for (int l0 = half*128; l0 < half*128 + 128; l0 += 4){
      float4 du01 = *(const float4*)&dtuT[dl][l0*2];
      float4 du23 = *(const float4*)&dtuT[dl][l0*2 + 4];
      float4 bc01 = *(const float4*)&BCT[s][l0*2];
      float4 bc23 = *(const float4*)&BCT[s][l0*2 + 4];
      float dtv[4] = {du01.x, du01.z, du23.x, du23.z};
      float uv[4]  = {du01.y, du01.w, du23.y, du23.w};
      float Bv[4]  = {bc01.x, bc01.z, bc23.x, bc23.z};
      float Cv[4]  = {bc01.y, bc01.w, bc23.y, bc23.w};
#pragma unroll
      for (int i = 0; i < 4; ++i){
        float a = __expf(dtv[i] * Av);
        h = fmaf(a, h, dtv[i]*uv[i]*Bv[i]);
        float p = h * Cv[i];
        float sum = row_sum16(p);
        if (s == 15){
          int lr = (l0 + i) & 127;
          ytile[lr][dl] = fmaf(uv[i], Dp, sum);
        }
      }
    }
    __syncthreads();
    // coalesced write-back of this half (rows flipped for dir=1)
    {
      int d4 = t & 3, lh = t >> 2;
      for (int pass = 0; pass < 2; ++pass){
        int lr = pass*64 + lh;
        int l = half*128 + lr;
        int lo = dir ? (255 - l) : l;
        float4 vv = *(const float4*)&ytile[lr][d4*4];
        *(float4*)(y + (size_t)(rbase + lo)*DI + dg*16 + d4*4) = vv;
      }
    }
    __syncthreads();
  }
}

// ---- final LayerNorm ----
__global__ __launch_bounds__(256) void ln_kernel(const float* __restrict__ x,
    const float* __restrict__ w, const float* __restrict__ bias,
    float* __restrict__ y){
  __shared__ float sc[8];
  int row = blockIdx.x, t = threadIdx.x;
  const float* xr = x + (size_t)row*DM;
  float v0 = xr[t], v1 = xr[t + 256];
  float s = v0 + v1, ss = v0*v0 + v1*v1;
  block_reduce2(s, ss, sc, 4);
  float mean = s * (1.f/512.f);
  float var = ss * (1.f/512.f) - mean*mean;
  float inv = rsqrtf(var + 1e-5f);
  float* yr = y + (size_t)row*DM;
  yr[t]       = (v0 - mean)*inv*w[t]       + bias[t];
  yr[t + 256] = (v1 - mean)*inv*w[t + 256] + bias[t + 256];
}

// ---- pool + LN + fc1/relu + fc2 ----
__global__ __launch_bounds__(512) void head_pool(const float* __restrict__ hn,
    const float* __restrict__ lnw, const float* __restrict__ lnb,
    const float* __restrict__ fc1w, const float* __restrict__ fc1b,
    const float* __restrict__ fc2w, const float* __restrict__ fc2b,
    float* __restrict__ out){
  __shared__ float sc[16];
  __shared__ float cbuf[512];
  __shared__ float rbuf[512];
  int b = blockIdx.x, t = threadIdx.x;
  float v = 0.f;
  for (int l = 0; l < 256; ++l) v += hn[(size_t)(b*256 + l)*512 + t];
  v *= (1.f/256.f);
  float s = v, ss = v*v;
  block_reduce2(s, ss, sc, 8);
  float mean = s * (1.f/512.f);
  float var = ss * (1.f/512.f) - mean*mean;
  float inv = rsqrtf(var + 1e-5f);
  cbuf[t] = (v - mean)*inv*lnw[t] + lnb[t];
  __syncthreads();
  float a = fc1b[t];
  const float* w1 = fc1w + (size_t)t*512;
  for (int i = 0; i < 512; i += 8){
    float4 w0 = *(const float4*)(w1 + i);
    float4 w4 = *(const float4*)(w1 + i + 4);
    float wf[8] = {w0.x,w0.y,w0.z,w0.w,w4.x,w4.y,w4.z,w4.w};
#pragma unroll
    for (int j = 0; j < 8; ++j) a = fmaf(cbuf[i + j], wf[j], a);
  }
  rbuf[t] = fmaxf(a, 0.f);
  __syncthreads();
  if (t < 10){
    float a2 = fc2b[t];
    const float* w2 = fc2w + (size_t)t*512;
    for (int i = 0; i < 512; ++i) a2 = fmaf(rbuf[i], w2[i], a2);
    out[b*10 + t] = a2;
  }
}

extern "C" void kernel_launch(void* const* d_in, const int* in_sizes, int n_in,
                              void* d_out, int out_size, void* d_ws, size_t ws_size,
                              hipStream_t stream) {
  (void)in_sizes; (void)n_in; (void)out_size; (void)ws_size;
  const float* x          = (const float*)d_in[0];
  const float* patch_w    = (const float*)d_in[1];
  const float* patch_b    = (const float*)d_in[2];
  const float* in_proj_w  = (const float*)d_in[3];
  const float* conv_w_f   = (const float*)d_in[4];
  const float* conv_b_f   = (const float*)d_in[5];
  const float* xproj_w_f  = (const float*)d_in[6];
  const float* dtproj_w_f = (const float*)d_in[7];
  const float* dtproj_b_f = (const float*)d_in[8];
  const float* A_log_f    = (const float*)d_in[9];
  const float* D_f        = (const float*)d_in[10];
  const float* conv_w_b   = (const float*)d_in[11];
  const float* conv_b_b   = (const float*)d_in[12];
  const float* xproj_w_b  = (const float*)d_in[13];
  const float* dtproj_w_b = (const float*)d_in[14];
  const float* dtproj_b_b = (const float*)d_in[15];
  const float* A_log_b    = (const float*)d_in[16];
  const float* D_b        = (const float*)d_in[17];
  const float* out_proj_w = (const float*)d_in[18];
  const float* norm_w     = (const float*)d_in[19];
  const float* norm_b     = (const float*)d_in[20];
  const float* normf_w    = (const float*)d_in[21];
  const float* normf_b    = (const float*)d_in[22];
  const float* ln_w       = (const float*)d_in[23];
  const float* ln_b       = (const float*)d_in[24];
  const float* fc1_w      = (const float*)d_in[25];
  const float* fc1_b      = (const float*)d_in[26];
  const float* fc2_w      = (const float*)d_in[27];
  const float* fc2_b      = (const float*)d_in[28];

  float* ws   = (float*)d_ws;
  float* hbuf = ws;                 // 524288
  float* xz   = ws + 524288;        // 2097152
  float* ubuf = ws + 2621440;       // 2097152 (2 dirs)
  float* xdbl = ws + 4718592;       // 131072  (2 dirs)
  float* dtb  = ws + 4849664;       // 2097152 (2 dirs)
  float* ybuf = ws + 6946816;       // 2097152 (2 dirs)
  float* hn   = ws + 9043968;       // 524288
  u16*   inHi = (u16*)(ws + 9568256);   // 1048576 u16
  u16*   inLo = (u16*)(ws + 10092544);  // 1048576 u16
  u16*   outHi= (u16*)(ws + 10616832);  // 524288 u16
  u16*   outLo= (u16*)(ws + 10878976);  // 524288 u16

  patch_embed<<<256, 256, 0, stream>>>(x, patch_w, patch_b, hbuf);
  for (int i = 0; i < 4; ++i){
    convert_w<<<1536, 256, 0, stream>>>(in_proj_w + (size_t)i*1048576,
                                        out_proj_w + (size_t)i*524288,
                                        inHi, inLo, outHi, outLo);
    gemm1_ln_mfma<<<dim3(32, 16), 256, 0, stream>>>(
        hbuf, norm_w, norm_b, i*512, inHi, inLo, xz);
    fused_cxd<<<512, 256, 0, stream>>>(
        xz, conv_w_f, conv_b_f, conv_w_b, conv_b_b, xproj_w_f, xproj_w_b,
        dtproj_w_f, dtproj_b_f, dtproj_w_b, dtproj_b_b,
        i*4096, i*1024, i*65536, i*32768, i*1024, ubuf, xdbl, dtb);
    scan_coal<<<512, 256, 0, stream>>>(
        dtb, ubuf, xdbl, A_log_f, A_log_b, D_f, D_b, i*16384, i*1024, ybuf);
    gemm2_gate_mfma<<<dim3(8, 16), 256, 0, stream>>>(
        ybuf, xz, outHi, outLo, hbuf);
  }
  ln_kernel<<<1024, 256, 0, stream>>>(hbuf, normf_w, normf_b, hn);
  head_pool<<<4, 512, 0, stream>>>(hn, ln_w, ln_b, fc1_w, fc1_b, fc2_w, fc2_b,
                                   (float*)d_out);
}

// Round 8
// 756.364 us; speedup vs baseline: 1.4789x; 1.0041x over previous
//
#include <hip/hip_runtime.h>

// AudioMamba forward, fp32 activations; big GEMMs via split-bf16 MFMA with
// LDS staging + pre-split weights. Scan: coalesced LDS-tiled chunk scan with
// DPP row reductions. Head: parallel pool + small head kernel.
// Inputs fp32, output fp32. B=4, L=256, DM=512, DI=1024, S=16, R=32, DEPTH=4.

#define BB 4
#define LL 256
#define DM 512
#define DI 1024

typedef unsigned short u16;
typedef unsigned int u32;
typedef __attribute__((ext_vector_type(8))) short s8v;   // 8 bf16 (4 VGPRs)
typedef __attribute__((ext_vector_type(4))) float f4v;   // MFMA accumulator

__device__ __forceinline__ float silu_f(float x){ return x/(1.f+__expf(-x)); }
__device__ __forceinline__ float b2f(u16 u){
  union { u32 i; float f; } v; v.i = ((u32)u) << 16; return v.f;
}
__device__ __forceinline__ u16 f2bf(float f){
  union { float f; u32 u; } v; v.f = f;
  u32 r = (v.u + 0x7fffu + ((v.u >> 16) & 1u)) >> 16;
  return (u16)r;
}
__device__ __forceinline__ void split8(const float* f, s8v& hi, s8v& lo){
#pragma unroll
  for (int j = 0; j < 8; ++j){
    u16 h = f2bf(f[j]);
    float hf = b2f(h);
    hi[j] = (short)h;
    lo[j] = (short)f2bf(f[j] - hf);
  }
}

// sum over 16-lane DPP row; full sum lands in lane 15 of each row (VALU-only)
__device__ __forceinline__ float row_sum16(float p){
  union { float f; int i; } v, r;
  v.f = p;
  r.i = __builtin_amdgcn_update_dpp(0, v.i, 0x111, 0xF, 0xF, true); v.f += r.f;
  r.i = __builtin_amdgcn_update_dpp(0, v.i, 0x112, 0xF, 0xF, true); v.f += r.f;
  r.i = __builtin_amdgcn_update_dpp(0, v.i, 0x114, 0xF, 0xF, true); v.f += r.f;
  r.i = __builtin_amdgcn_update_dpp(0, v.i, 0x118, 0xF, 0xF, true); v.f += r.f;
  return v.f;
}

__device__ __forceinline__ void block_reduce2(float& a, float& b, float* sc, int nw){
  int lane = threadIdx.x & 63, wid = threadIdx.x >> 6;
#pragma unroll
  for (int o = 32; o > 0; o >>= 1){
    a += __shfl_down(a, o, 64);
    b += __shfl_down(b, o, 64);
  }
  if (lane == 0){ sc[wid*2] = a; sc[wid*2+1] = b; }
  __syncthreads();
  float ta = 0.f, tb = 0.f;
  for (int i = 0; i < nw; ++i){ ta += sc[i*2]; tb += sc[i*2+1]; }
  a = ta; b = tb;
}

// ---- per-layer weight split ----
__global__ __launch_bounds__(256) void convert_w(const float* __restrict__ inW,
    const float* __restrict__ outW, u16* __restrict__ inHi, u16* __restrict__ inLo,
    u16* __restrict__ outHi, u16* __restrict__ outLo){
  int idx = blockIdx.x*256 + threadIdx.x;
  const float4* src; ushort4* dh; ushort4* dl;
  if (idx < 262144){
    src = (const float4*)inW + idx;
    dh = (ushort4*)inHi + idx; dl = (ushort4*)inLo + idx;
  } else {
    int j = idx - 262144;
    src = (const float4*)outW + j;
    dh = (ushort4*)outHi + j; dl = (ushort4*)outLo + j;
  }
  float4 v = *src;
  ushort4 h, l;
  h.x = f2bf(v.x); l.x = f2bf(v.x - b2f(h.x));
  h.y = f2bf(v.y); l.y = f2bf(v.y - b2f(h.y));
  h.z = f2bf(v.z); l.z = f2bf(v.z - b2f(h.z));
  h.w = f2bf(v.w); l.w = f2bf(v.w - b2f(h.w));
  *dh = h; *dl = l;
}

// ---- patch embed: 256 blocks (b4, ph8, pg4, dhalf2); 8 tokens per block ----
__global__ __launch_bounds__(256) void patch_embed(const float* __restrict__ x,
    const float* __restrict__ pw, const float* __restrict__ pb, float* __restrict__ h){
  __shared__ float xs[8*256];
  int blk = blockIdx.x;
  int b = blk >> 6, ph = (blk >> 3) & 7, pg = (blk >> 1) & 3, dh = blk & 1;
  int t = threadIdx.x;
  for (int idx = t; idx < 2048; idx += 256){
    int j = idx >> 8, pix = idx & 255, p = pix >> 4, q = pix & 15;
    xs[idx] = x[(size_t)(b*128 + ph*16 + p)*512 + pg*128 + j*16 + q];
  }
  __syncthreads();
  int d = dh*256 + t;
  float acc[8] = {};
  const float* wr = pw + (size_t)d*256;
  for (int i = 0; i < 256; i += 8){
    float4 w0 = *(const float4*)(wr + i);
    float4 w1 = *(const float4*)(wr + i + 4);
    float wf[8] = {w0.x,w0.y,w0.z,w0.w,w1.x,w1.y,w1.z,w1.w};
#pragma unroll
    for (int j = 0; j < 8; ++j){
#pragma unroll
      for (int jj = 0; jj < 8; ++jj)
        acc[j] = fmaf(xs[j*256 + i + jj], wf[jj], acc[j]);
    }
  }
  float bias = pb[d];
#pragma unroll
  for (int j = 0; j < 8; ++j)
    h[(size_t)(b*256 + ph*32 + pg*8 + j)*512 + d] = acc[j] + bias;
}

// ---- in_proj via LDS-staged MFMA, LN fused into A staging ----
__global__ __launch_bounds__(256) void gemm1_ln_mfma(const float* __restrict__ X,
    const float* __restrict__ lnw, const float* __restrict__ lnb, int lnOff,
    const u16* __restrict__ Whi, const u16* __restrict__ Wlo, float* __restrict__ C){
  __shared__ __align__(16) u16 Ah[2048], Al[2048], Bh[2048], Bl[2048];
  __shared__ float rmean[64], rrstd[64];
  int bm = blockIdx.y*64, bn = blockIdx.x*64;
  int t = threadIdx.x;
  int sr = t >> 2, sc = (t & 3)*8;
  {
    const float* xr = X + (size_t)(bm + sr)*512 + (t & 3)*128;
    float s = 0.f, ss = 0.f;
    for (int i = 0; i < 128; i += 4){
      float4 v = *(const float4*)(xr + i);
      s  += v.x + v.y + v.z + v.w;
      ss += v.x*v.x + v.y*v.y + v.z*v.z + v.w*v.w;
    }
    s += __shfl_xor(s, 1, 64); ss += __shfl_xor(ss, 1, 64);
    s += __shfl_xor(s, 2, 64); ss += __shfl_xor(ss, 2, 64);
    if ((t & 3) == 0){
      float m = s * (1.f/512.f);
      float var = ss * (1.f/512.f) - m*m;
      rmean[sr] = m; rrstd[sr] = rsqrtf(var + 1e-5f);
    }
  }
  __syncthreads();
  float mm = rmean[sr], rr = rrstd[sr];
  int lane = t & 63, wv = t >> 6, ml = lane & 15, quad = lane >> 4;
  int mq = wv >> 1, nq = wv & 1;
  f4v acc[2][2] = {};
  for (int k0 = 0; k0 < 512; k0 += 32){
    const float* xr = X + (size_t)(bm + sr)*512 + k0 + sc;
    float4 a0 = *(const float4*)xr;
    float4 a1 = *(const float4*)(xr + 4);
    float4 g0 = *(const float4*)(lnw + lnOff + k0 + sc);
    float4 g1 = *(const float4*)(lnw + lnOff + k0 + sc + 4);
    float4 c0 = *(const float4*)(lnb + lnOff + k0 + sc);
    float4 c1 = *(const float4*)(lnb + lnOff + k0 + sc + 4);
    float af[8] = {
      (a0.x-mm)*rr*g0.x + c0.x, (a0.y-mm)*rr*g0.y + c0.y,
      (a0.z-mm)*rr*g0.z + c0.z, (a0.w-mm)*rr*g0.w + c0.w,
      (a1.x-mm)*rr*g1.x + c1.x, (a1.y-mm)*rr*g1.y + c1.y,
      (a1.z-mm)*rr*g1.z + c1.z, (a1.w-mm)*rr*g1.w + c1.w };
    s8v ahv, alv; split8(af, ahv, alv);
    *(s8v*)&Ah[sr*32 + sc] = ahv;
    *(s8v*)&Al[sr*32 + sc] = alv;
    uint4 bhv = *(const uint4*)(Whi + (size_t)(bn + sr)*512 + k0 + sc);
    uint4 blv = *(const uint4*)(Wlo + (size_t)(bn + sr)*512 + k0 + sc);
    *(uint4*)&Bh[sr*32 + sc] = bhv;
    *(uint4*)&Bl[sr*32 + sc] = blv;
    __syncthreads();
    s8v ah[2], al2[2], bh2[2], bl2[2];
#pragma unroll
    for (int mt = 0; mt < 2; ++mt){
      int row = mq*32 + mt*16 + ml;
      ah[mt]  = *(s8v*)&Ah[row*32 + quad*8];
      al2[mt] = *(s8v*)&Al[row*32 + quad*8];
    }
#pragma unroll
    for (int nt = 0; nt < 2; ++nt){
      int col = nq*32 + nt*16 + ml;
      bh2[nt] = *(s8v*)&Bh[col*32 + quad*8];
      bl2[nt] = *(s8v*)&Bl[col*32 + quad*8];
    }
#pragma unroll
    for (int mt = 0; mt < 2; ++mt)
#pragma unroll
      for (int nt = 0; nt < 2; ++nt){
        acc[mt][nt] = __builtin_amdgcn_mfma_f32_16x16x32_bf16(ah[mt],  bh2[nt], acc[mt][nt], 0, 0, 0);
        acc[mt][nt] = __builtin_amdgcn_mfma_f32_16x16x32_bf16(al2[mt], bh2[nt], acc[mt][nt], 0, 0, 0);
        acc[mt][nt] = __builtin_amdgcn_mfma_f32_16x16x32_bf16(ah[mt],  bl2[nt], acc[mt][nt], 0, 0, 0);
      }
    __syncthreads();
  }
#pragma unroll
  for (int mt = 0; mt < 2; ++mt)
#pragma unroll
    for (int nt = 0; nt < 2; ++nt)
#pragma unroll
      for (int r = 0; r < 4; ++r)
        C[(size_t)(bm + mq*32 + mt*16 + quad*4 + r)*2048 + bn + nq*32 + nt*16 + ml] =
            acc[mt][nt][r];
}

// ---- out_proj via LDS-staged MFMA, gate fused, residual += ----
__global__ __launch_bounds__(256) void gemm2_gate_mfma(const float* __restrict__ yb2,
    const float* __restrict__ xz, const u16* __restrict__ Whi,
    const u16* __restrict__ Wlo, float* __restrict__ C){
  __shared__ __align__(16) u16 Ah[2048], Al[2048], Bh[2048], Bl[2048];
  int bm = blockIdx.y*64, bn = blockIdx.x*64;
  int t = threadIdx.x;
  int sr = t >> 2, sc = (t & 3)*8;
  int lane = t & 63, wv = t >> 6, ml = lane & 15, quad = lane >> 4;
  int mq = wv >> 1, nq = wv & 1;
  f4v acc[2][2] = {};
  for (int k0 = 0; k0 < 1024; k0 += 32){
    int m = bm + sr;
    const float* fp = yb2 + (size_t)m*DI + k0 + sc;
    const float* rp = yb2 + (size_t)(1024 + m)*DI + k0 + sc;
    const float* zp = xz + (size_t)m*2048 + 1024 + k0 + sc;
    float4 f0 = *(const float4*)fp,       f1 = *(const float4*)(fp + 4);
    float4 r0 = *(const float4*)rp,       r1 = *(const float4*)(rp + 4);
    float4 z0 = *(const float4*)zp,       z1 = *(const float4*)(zp + 4);
    float af[8] = {
      (f0.x+r0.x)*silu_f(z0.x), (f0.y+r0.y)*silu_f(z0.y),
      (f0.z+r0.z)*silu_f(z0.z), (f0.w+r0.w)*silu_f(z0.w),
      (f1.x+r1.x)*silu_f(z1.x), (f1.y+r1.y)*silu_f(z1.y),
      (f1.z+r1.z)*silu_f(z1.z), (f1.w+r1.w)*silu_f(z1.w) };
    s8v ahv, alv; split8(af, ahv, alv);
    *(s8v*)&Ah[sr*32 + sc] = ahv;
    *(s8v*)&Al[sr*32 + sc] = alv;
    uint4 bhv = *(const uint4*)(Whi + (size_t)(bn + sr)*1024 + k0 + sc);
    uint4 blv = *(const uint4*)(Wlo + (size_t)(bn + sr)*1024 + k0 + sc);
    *(uint4*)&Bh[sr*32 + sc] = bhv;
    *(uint4*)&Bl[sr*32 + sc] = blv;
    __syncthreads();
    s8v ah[2], al2[2], bh2[2], bl2[2];
#pragma unroll
    for (int mt = 0; mt < 2; ++mt){
      int row = mq*32 + mt*16 + ml;
      ah[mt]  = *(s8v*)&Ah[row*32 + quad*8];
      al2[mt] = *(s8v*)&Al[row*32 + quad*8];
    }
#pragma unroll
    for (int nt = 0; nt < 2; ++nt){
      int col = nq*32 + nt*16 + ml;
      bh2[nt] = *(s8v*)&Bh[col*32 + quad*8];
      bl2[nt] = *(s8v*)&Bl[col*32 + quad*8];
    }
#pragma unroll
    for (int mt = 0; mt < 2; ++mt)
#pragma unroll
      for (int nt = 0; nt < 2; ++nt){
        acc[mt][nt] = __builtin_amdgcn_mfma_f32_16x16x32_bf16(ah[mt],  bh2[nt], acc[mt][nt], 0, 0, 0);
        acc[mt][nt] = __builtin_amdgcn_mfma_f32_16x16x32_bf16(al2[mt], bh2[nt], acc[mt][nt], 0, 0, 0);
        acc[mt][nt] = __builtin_amdgcn_mfma_f32_16x16x32_bf16(ah[mt],  bl2[nt], acc[mt][nt], 0, 0, 0);
      }
    __syncthreads();
  }
#pragma unroll
  for (int mt = 0; mt < 2; ++mt)
#pragma unroll
    for (int nt = 0; nt < 2; ++nt)
#pragma unroll
      for (int r = 0; r < 4; ++r){
        float* cp = C + (size_t)(bm + mq*32 + mt*16 + quad*4 + r)*512 +
                    bn + nq*32 + nt*16 + ml;
        *cp += acc[mt][nt][r];
      }
}

// ---- fused conv+silu -> xproj -> dtproj+softplus; block per (dir,b, 4 l's) ----
__global__ __launch_bounds__(256) void fused_cxd(const float* __restrict__ xz,
    const float* __restrict__ cwF, const float* __restrict__ cbF,
    const float* __restrict__ cwB, const float* __restrict__ cbB,
    const float* __restrict__ xwF, const float* __restrict__ xwB,
    const float* __restrict__ dtwF, const float* __restrict__ dtbF,
    const float* __restrict__ dtwB, const float* __restrict__ dtbB,
    int cwOff, int cbOff, int xwOff, int dtwOff, int dtbOff,
    float* __restrict__ u, float* __restrict__ xdbl, float* __restrict__ dtout){
  __shared__ float us[4*1024];
  __shared__ float part[16*64];
  __shared__ float dtr[4*32];
  int blk = blockIdx.x;
  int dir = blk >> 8, rem = blk & 255, b = rem >> 6, lg = rem & 63;
  int l0 = lg*4;
  const float* cw  = dir ? cwB  : cwF;
  const float* cb  = dir ? cbB  : cbF;
  const float* xw  = dir ? xwB  : xwF;
  const float* dtw = dir ? dtwB : dtwF;
  const float* dtb = dir ? dtbB : dtbF;
  int t = threadIdx.x;
  int rbase = (dir*BB + b)*LL;
  for (int dd = 0; dd < 4; ++dd){
    int d = t + dd*256;
    float4 w4 = *(const float4*)(cw + cwOff + d*4);
    float wf[4] = {w4.x, w4.y, w4.z, w4.w};
    float bias = cb[cbOff + d];
#pragma unroll
    for (int r = 0; r < 4; ++r){
      int l = l0 + r;
      float acc = bias;
#pragma unroll
      for (int k = 0; k < 4; ++k){
        int li = l + k - 3;
        if (li >= 0){
          int sl = dir ? (LL-1-li) : li;
          acc = fmaf(xz[(size_t)(b*LL + sl)*2048 + d], wf[k], acc);
        }
      }
      float uval = silu_f(acc);
      us[r*1024 + d] = uval;
      u[(size_t)(rbase + l)*DI + d] = uval;
    }
  }
  __syncthreads();
  {
    int e = t & 63, pr = t >> 6;
    float accs[4] = {};
    const float* wr = xw + xwOff + (size_t)e*1024 + pr*256;
    for (int i = 0; i < 256; i += 8){
      float4 w0 = *(const float4*)(wr + i);
      float4 w1 = *(const float4*)(wr + i + 4);
      float wf[8] = {w0.x,w0.y,w0.z,w0.w,w1.x,w1.y,w1.z,w1.w};
#pragma unroll
      for (int r = 0; r < 4; ++r){
        const float* ub = us + r*1024 + pr*256 + i;
#pragma unroll
        for (int j = 0; j < 8; ++j)
          accs[r] = fmaf(ub[j], wf[j], accs[r]);
      }
    }
#pragma unroll
    for (int r = 0; r < 4; ++r) part[(pr*4 + r)*64 + e] = accs[r];
  }
  __syncthreads();
  {
    int r = t >> 6, e = t & 63;
    float v = part[(0*4+r)*64+e] + part[(1*4+r)*64+e] +
              part[(2*4+r)*64+e] + part[(3*4+r)*64+e];
    xdbl[(size_t)(rbase + l0 + r)*64 + e] = v;
    if (e < 32) dtr[r*32 + e] = v;
  }
  __syncthreads();
  for (int dd = 0; dd < 4; ++dd){
    int d = t + dd*256;
    float bias = dtb[dtbOff + d];
    float accs[4] = {bias, bias, bias, bias};
    const float* wr = dtw + dtwOff + (size_t)d*32;
    for (int i = 0; i < 32; i += 8){
      float4 w0 = *(const float4*)(wr + i);
      float4 w1 = *(const float4*)(wr + i + 4);
      float wf[8] = {w0.x,w0.y,w0.z,w0.w,w1.x,w1.y,w1.z,w1.w};
#pragma unroll
      for (int r = 0; r < 4; ++r)
#pragma unroll
        for (int j = 0; j < 8; ++j)
          accs[r] = fmaf(dtr[r*32 + i + j], wf[j], accs[r]);
    }
#pragma unroll
    for (int r = 0; r < 4; ++r){
      float sv = accs[r];
      dtout[(size_t)(rbase + l0 + r)*DI + d] = (sv > 15.f) ? sv : log1pf(__expf(sv));
    }
  }
}

// ---- coalesced LDS-tiled selective scan ----
__global__ __launch_bounds__(256) void scan_coal(const float* __restrict__ dt,
    const float* __restrict__ u, const float* __restrict__ xd,
    const float* __restrict__ AlogF, const float* __restrict__ AlogB,
    const float* __restrict__ DF, const float* __restrict__ DB,
    int aOff, int dOff, float* __restrict__ y){
  __shared__ __align__(16) float dtuT[16][516];  // [d][(dt,u) per l], pad rows
  __shared__ __align__(16) float BCT[16][516];   // [s][(B,C) per l]
  __shared__ __align__(16) float ytile[128][16];
  int blk = blockIdx.x;
  int dir = blk >> 8, b = (blk >> 6) & 3, dg = blk & 63;
  int t = threadIdx.x;
  int rbase = (dir*BB + b)*LL;
  const float* Alog = dir ? AlogB : AlogF;
  const float* Dpt  = dir ? DB : DF;
  {
    int q = t & 3, lb = t >> 2;
    for (int pass = 0; pass < 4; ++pass){
      int l = pass*64 + lb;
      float4 dv = *(const float4*)(dt + (size_t)(rbase + l)*DI + dg*16 + q*4);
      float4 uv = *(const float4*)(u  + (size_t)(rbase + l)*DI + dg*16 + q*4);
      float2 p0 = {dv.x, uv.x}, p1 = {dv.y, uv.y}, p2 = {dv.z, uv.z}, p3 = {dv.w, uv.w};
      *(float2*)&dtuT[q*4+0][l*2] = p0;
      *(float2*)&dtuT[q*4+1][l*2] = p1;
      *(float2*)&dtuT[q*4+2][l*2] = p2;
      *(float2*)&dtuT[q*4+3][l*2] = p3;
    }
  }
  {
    int h8 = t & 7, lb = t >> 3;
    for (int pass = 0; pass < 8; ++pass){
      int l = pass*32 + lb;
      float4 v = *(const float4*)(xd + (size_t)(rbase + l)*64 + 32 + h8*4);
      if (h8 < 4){
        int s0 = h8*4;
        BCT[s0+0][l*2] = v.x; BCT[s0+1][l*2] = v.y;
        BCT[s0+2][l*2] = v.z; BCT[s0+3][l*2] = v.w;
      } else {
        int s0 = (h8-4)*4;
        BCT[s0+0][l*2+1] = v.x; BCT[s0+1][l*2+1] = v.y;
        BCT[s0+2][l*2+1] = v.z; BCT[s0+3][l*2+1] = v.w;
      }
    }
  }
  int s = t & 15, dl = t >> 4;
  float Av = -__expf(Alog[aOff + dg*256 + t]);
  float Dp = Dpt[dOff + dg*16 + dl];
  __syncthreads();
  float h = 0.f;
  for (int half = 0; half < 2; ++half){
    for (int l0 = half*128; l0 < half*128 + 128; l0 += 4){
      float4 du01 = *(const float4*)&dtuT[dl][l0*2];
      float4 du23 = *(const float4*)&dtuT[dl][l0*2 + 4];
      float4 bc01 = *(const float4*)&BCT[s][l0*2];
      float4 bc23 = *(const float4*)&BCT[s][l0*2 + 4];
      float dtv[4] = {du01.x, du01.z, du23.x, du23.z};
      float uv[4]  = {du01.y, du01.w, du23.y, du23.w};
      float Bv[4]  = {bc01.x, bc01.z, bc23.x, bc23.z};
      float Cv[4]  = {bc01.y, bc01.w, bc23.y, bc23.w};
#pragma unroll
      for (int i = 0; i < 4; ++i){
        float a = __expf(dtv[i] * Av);
        h = fmaf(a, h, dtv[i]*uv[i]*Bv[i]);
        float p = h * Cv[i];
        float sum = row_sum16(p);
        if (s == 15){
          int lr = (l0 + i) & 127;
          ytile[lr][dl] = fmaf(uv[i], Dp, sum);
        }
      }
    }
    __syncthreads();
    {
      int d4 = t & 3, lh = t >> 2;
      for (int pass = 0; pass < 2; ++pass){
        int lr = pass*64 + lh;
        int l = half*128 + lr;
        int lo = dir ? (255 - l) : l;
        float4 vv = *(const float4*)&ytile[lr][d4*4];
        *(float4*)(y + (size_t)(rbase + lo)*DI + dg*16 + d4*4) = vv;
      }
    }
    __syncthreads();
  }
}

// ---- final LayerNorm ----
__global__ __launch_bounds__(256) void ln_kernel(const float* __restrict__ x,
    const float* __restrict__ w, const float* __restrict__ bias,
    float* __restrict__ y){
  __shared__ float sc[8];
  int row = blockIdx.x, t = threadIdx.x;
  const float* xr = x + (size_t)row*DM;
  float v0 = xr[t], v1 = xr[t + 256];
  float s = v0 + v1, ss = v0*v0 + v1*v1;
  block_reduce2(s, ss, sc, 4);
  float mean = s * (1.f/512.f);
  float var = ss * (1.f/512.f) - mean*mean;
  float inv = rsqrtf(var + 1e-5f);
  float* yr = y + (size_t)row*DM;
  yr[t]       = (v0 - mean)*inv*w[t]       + bias[t];
  yr[t + 256] = (v1 - mean)*inv*w[t + 256] + bias[t + 256];
}

// ---- pool: mean over L, coalesced; 32 blocks (4 b x 8 d-groups) ----
__global__ __launch_bounds__(256) void pool_kernel(const float* __restrict__ hn,
    float* __restrict__ feat){
  __shared__ float part[4][64];
  int b = blockIdx.x >> 3, dg = blockIdx.x & 7;
  int t = threadIdx.x, dl = t & 63, lq = t >> 6;
  const float* p = hn + (size_t)(b*256 + lq*64)*512 + dg*64 + dl;
  float s = 0.f;
#pragma unroll 4
  for (int i = 0; i < 64; ++i) s += p[(size_t)i*512];
  part[lq][dl] = s;
  __syncthreads();
  if (t < 64)
    feat[b*512 + dg*64 + t] =
        (part[0][t] + part[1][t] + part[2][t] + part[3][t]) * (1.f/256.f);
}

// ---- head: LN + fc1/relu + fc2; 4 blocks ----
__global__ __launch_bounds__(512) void head_kernel(const float* __restrict__ feat,
    const float* __restrict__ lnw, const float* __restrict__ lnb,
    const float* __restrict__ fc1w, const float* __restrict__ fc1b,
    const float* __restrict__ fc2w, const float* __restrict__ fc2b,
    float* __restrict__ out){
  __shared__ float sc[16];
  __shared__ float cbuf[512];
  __shared__ float rbuf[512];
  int b = blockIdx.x, t = threadIdx.x;
  float v = feat[b*512 + t];
  float s = v, ss = v*v;
  block_reduce2(s, ss, sc, 8);
  float mean = s * (1.f/512.f);
  float var = ss * (1.f/512.f) - mean*mean;
  float inv = rsqrtf(var + 1e-5f);
  cbuf[t] = (v - mean)*inv*lnw[t] + lnb[t];
  __syncthreads();
  float a = fc1b[t];
  const float* w1 = fc1w + (size_t)t*512;
  for (int i = 0; i < 512; i += 8){
    float4 w0 = *(const float4*)(w1 + i);
    float4 w4 = *(const float4*)(w1 + i + 4);
    float wf[8] = {w0.x,w0.y,w0.z,w0.w,w4.x,w4.y,w4.z,w4.w};
#pragma unroll
    for (int j = 0; j < 8; ++j) a = fmaf(cbuf[i + j], wf[j], a);
  }
  rbuf[t] = fmaxf(a, 0.f);
  __syncthreads();
  if (t < 10){
    float a2 = fc2b[t];
    const float* w2 = fc2w + (size_t)t*512;
    for (int i = 0; i < 512; ++i) a2 = fmaf(rbuf[i], w2[i], a2);
    out[b*10 + t] = a2;
  }
}

extern "C" void kernel_launch(void* const* d_in, const int* in_sizes, int n_in,
                              void* d_out, int out_size, void* d_ws, size_t ws_size,
                              hipStream_t stream) {
  (void)in_sizes; (void)n_in; (void)out_size; (void)ws_size;
  const float* x          = (const float*)d_in[0];
  const float* patch_w    = (const float*)d_in[1];
  const float* patch_b    = (const float*)d_in[2];
  const float* in_proj_w  = (const float*)d_in[3];
  const float* conv_w_f   = (const float*)d_in[4];
  const float* conv_b_f   = (const float*)d_in[5];
  const float* xproj_w_f  = (const float*)d_in[6];
  const float* dtproj_w_f = (const float*)d_in[7];
  const float* dtproj_b_f = (const float*)d_in[8];
  const float* A_log_f    = (const float*)d_in[9];
  const float* D_f        = (const float*)d_in[10];
  const float* conv_w_b   = (const float*)d_in[11];
  const float* conv_b_b   = (const float*)d_in[12];
  const float* xproj_w_b  = (const float*)d_in[13];
  const float* dtproj_w_b = (const float*)d_in[14];
  const float* dtproj_b_b = (const float*)d_in[15];
  const float* A_log_b    = (const float*)d_in[16];
  const float* D_b        = (const float*)d_in[17];
  const float* out_proj_w = (const float*)d_in[18];
  const float* norm_w     = (const float*)d_in[19];
  const float* norm_b     = (const float*)d_in[20];
  const float* normf_w    = (const float*)d_in[21];
  const float* normf_b    = (const float*)d_in[22];
  const float* ln_w       = (const float*)d_in[23];
  const float* ln_b       = (const float*)d_in[24];
  const float* fc1_w      = (const float*)d_in[25];
  const float* fc1_b      = (const float*)d_in[26];
  const float* fc2_w      = (const float*)d_in[27];
  const float* fc2_b      = (const float*)d_in[28];

  float* ws   = (float*)d_ws;
  float* hbuf = ws;                 // 524288
  float* xz   = ws + 524288;        // 2097152
  float* ubuf = ws + 2621440;       // 2097152 (2 dirs)
  float* xdbl = ws + 4718592;       // 131072  (2 dirs)
  float* dtb  = ws + 4849664;       // 2097152 (2 dirs)
  float* ybuf = ws + 6946816;       // 2097152 (2 dirs)
  float* hn   = ws + 9043968;       // 524288
  u16*   inHi = (u16*)(ws + 9568256);   // 1048576 u16
  u16*   inLo = (u16*)(ws + 10092544);  // 1048576 u16
  u16*   outHi= (u16*)(ws + 10616832);  // 524288 u16
  u16*   outLo= (u16*)(ws + 10878976);  // 524288 u16
  float* feat = ws + 11141120;          // 2048

  patch_embed<<<256, 256, 0, stream>>>(x, patch_w, patch_b, hbuf);
  for (int i = 0; i < 4; ++i){
    convert_w<<<1536, 256, 0, stream>>>(in_proj_w + (size_t)i*1048576,
                                        out_proj_w + (size_t)i*524288,
                                        inHi, inLo, outHi, outLo);
    gemm1_ln_mfma<<<dim3(32, 16), 256, 0, stream>>>(
        hbuf, norm_w, norm_b, i*512, inHi, inLo, xz);
    fused_cxd<<<512, 256, 0, stream>>>(
        xz, conv_w_f, conv_b_f, conv_w_b, conv_b_b, xproj_w_f, xproj_w_b,
        dtproj_w_f, dtproj_b_f, dtproj_w_b, dtproj_b_b,
        i*4096, i*1024, i*65536, i*32768, i*1024, ubuf, xdbl, dtb);
    scan_coal<<<512, 256, 0, stream>>>(
        dtb, ubuf, xdbl, A_log_f, A_log_b, D_f, D_b, i*16384, i*1024, ybuf);
    gemm2_gate_mfma<<<dim3(8, 16), 256, 0, stream>>>(
        ybuf, xz, outHi, outLo, hbuf);
  }
  ln_kernel<<<1024, 256, 0, stream>>>(hbuf, normf_w, normf_b, hn);
  pool_kernel<<<32, 256, 0, stream>>>(hn, feat);
  head_kernel<<<4, 512, 0, stream>>>(feat, ln_w, ln_b, fc1_w, fc1_b, fc2_w, fc2_b,
                                     (float*)d_out);
}

// Round 9
// 664.199 us; speedup vs baseline: 1.6841x; 1.1388x over previous
//
#include <hip/hip_runtime.h>

// AudioMamba forward, fp32 activations; GEMMs = pure pre-split bf16 MFMA
// (hi/lo, 3 MFMAs, fp32-accurate) with padded LDS (stride 40 u16, no 8-way
// conflicts). LN and gate hoisted into prep kernels (no redundant A fetch).
// Inputs fp32, output fp32. B=4, L=256, DM=512, DI=1024, S=16, R=32, DEPTH=4.

#define BB 4
#define LL 256
#define DM 512
#define DI 1024
#define LDST 40   // LDS row stride in u16 (pad 32->40 kills bank conflicts)

typedef unsigned short u16;
typedef unsigned int u32;
typedef __attribute__((ext_vector_type(8))) short s8v;   // 8 bf16 (4 VGPRs)
typedef __attribute__((ext_vector_type(4))) float f4v;   // MFMA accumulator

__device__ __forceinline__ float silu_f(float x){ return x/(1.f+__expf(-x)); }
__device__ __forceinline__ float b2f(u16 u){
  union { u32 i; float f; } v; v.i = ((u32)u) << 16; return v.f;
}
__device__ __forceinline__ u16 f2bf(float f){
  union { float f; u32 u; } v; v.f = f;
  u32 r = (v.u + 0x7fffu + ((v.u >> 16) & 1u)) >> 16;
  return (u16)r;
}

// sum over 16-lane DPP row; full sum lands in lane 15 of each row (VALU-only)
__device__ __forceinline__ float row_sum16(float p){
  union { float f; int i; } v, r;
  v.f = p;
  r.i = __builtin_amdgcn_update_dpp(0, v.i, 0x111, 0xF, 0xF, true); v.f += r.f;
  r.i = __builtin_amdgcn_update_dpp(0, v.i, 0x112, 0xF, 0xF, true); v.f += r.f;
  r.i = __builtin_amdgcn_update_dpp(0, v.i, 0x114, 0xF, 0xF, true); v.f += r.f;
  r.i = __builtin_amdgcn_update_dpp(0, v.i, 0x118, 0xF, 0xF, true); v.f += r.f;
  return v.f;
}

__device__ __forceinline__ void block_reduce2(float& a, float& b, float* sc, int nw){
  int lane = threadIdx.x & 63, wid = threadIdx.x >> 6;
#pragma unroll
  for (int o = 32; o > 0; o >>= 1){
    a += __shfl_down(a, o, 64);
    b += __shfl_down(b, o, 64);
  }
  if (lane == 0){ sc[wid*2] = a; sc[wid*2+1] = b; }
  __syncthreads();
  float ta = 0.f, tb = 0.f;
  for (int i = 0; i < nw; ++i){ ta += sc[i*2]; tb += sc[i*2+1]; }
  a = ta; b = tb;
}

// ---- per-layer weight split ----
__global__ __launch_bounds__(256) void convert_w(const float* __restrict__ inW,
    const float* __restrict__ outW, u16* __restrict__ inHi, u16* __restrict__ inLo,
    u16* __restrict__ outHi, u16* __restrict__ outLo){
  int idx = blockIdx.x*256 + threadIdx.x;
  const float4* src; ushort4* dh; ushort4* dl;
  if (idx < 262144){
    src = (const float4*)inW + idx;
    dh = (ushort4*)inHi + idx; dl = (ushort4*)inLo + idx;
  } else {
    int j = idx - 262144;
    src = (const float4*)outW + j;
    dh = (ushort4*)outHi + j; dl = (ushort4*)outLo + j;
  }
  float4 v = *src;
  ushort4 h, l;
  h.x = f2bf(v.x); l.x = f2bf(v.x - b2f(h.x));
  h.y = f2bf(v.y); l.y = f2bf(v.y - b2f(h.y));
  h.z = f2bf(v.z); l.z = f2bf(v.z - b2f(h.z));
  h.w = f2bf(v.w); l.w = f2bf(v.w - b2f(h.w));
  *dh = h; *dl = l;
}

// ---- patch embed: 256 blocks (b4, ph8, pg4, dhalf2); 8 tokens per block ----
__global__ __launch_bounds__(256) void patch_embed(const float* __restrict__ x,
    const float* __restrict__ pw, const float* __restrict__ pb, float* __restrict__ h){
  __shared__ float xs[8*256];
  int blk = blockIdx.x;
  int b = blk >> 6, ph = (blk >> 3) & 7, pg = (blk >> 1) & 3, dh = blk & 1;
  int t = threadIdx.x;
  for (int idx = t; idx < 2048; idx += 256){
    int j = idx >> 8, pix = idx & 255, p = pix >> 4, q = pix & 15;
    xs[idx] = x[(size_t)(b*128 + ph*16 + p)*512 + pg*128 + j*16 + q];
  }
  __syncthreads();
  int d = dh*256 + t;
  float acc[8] = {};
  const float* wr = pw + (size_t)d*256;
  for (int i = 0; i < 256; i += 8){
    float4 w0 = *(const float4*)(wr + i);
    float4 w1 = *(const float4*)(wr + i + 4);
    float wf[8] = {w0.x,w0.y,w0.z,w0.w,w1.x,w1.y,w1.z,w1.w};
#pragma unroll
    for (int j = 0; j < 8; ++j){
#pragma unroll
      for (int jj = 0; jj < 8; ++jj)
        acc[j] = fmaf(xs[j*256 + i + jj], wf[jj], acc[j]);
    }
  }
  float bias = pb[d];
#pragma unroll
  for (int j = 0; j < 8; ++j)
    h[(size_t)(b*256 + ph*32 + pg*8 + j)*512 + d] = acc[j] + bias;
}

// ---- prep_ln: LN(h) -> bf16 hi/lo; one block per token row ----
__global__ __launch_bounds__(256) void prep_ln(const float* __restrict__ x,
    const float* __restrict__ w, const float* __restrict__ bias, int wOff,
    u16* __restrict__ hiO, u16* __restrict__ loO){
  __shared__ float sc[8];
  int row = blockIdx.x, t = threadIdx.x;
  const float* xr = x + (size_t)row*DM;
  float v0 = xr[t], v1 = xr[t + 256];
  float s = v0 + v1, ss = v0*v0 + v1*v1;
  block_reduce2(s, ss, sc, 4);
  float mean = s * (1.f/512.f);
  float var = ss * (1.f/512.f) - mean*mean;
  float inv = rsqrtf(var + 1e-5f);
  float o0 = (v0 - mean)*inv*w[wOff + t]       + bias[wOff + t];
  float o1 = (v1 - mean)*inv*w[wOff + t + 256] + bias[wOff + t + 256];
  u16 h0 = f2bf(o0), h1 = f2bf(o1);
  hiO[(size_t)row*DM + t]       = h0;
  hiO[(size_t)row*DM + t + 256] = h1;
  loO[(size_t)row*DM + t]       = f2bf(o0 - b2f(h0));
  loO[(size_t)row*DM + t + 256] = f2bf(o1 - b2f(h1));
}

// ---- prep_gate: g = (yf+yb)*silu(z) -> bf16 hi/lo; one block per row ----
__global__ __launch_bounds__(256) void prep_gate(const float* __restrict__ ybuf,
    const float* __restrict__ xz, u16* __restrict__ gHi, u16* __restrict__ gLo){
  int row = blockIdx.x, t = threadIdx.x;
  int c = t*4;
  float4 yf = *(const float4*)(ybuf + (size_t)row*DI + c);
  float4 yb = *(const float4*)(ybuf + 1048576 + (size_t)row*DI + c);
  float4 zv = *(const float4*)(xz + (size_t)row*2048 + 1024 + c);
  float g0 = (yf.x + yb.x)*silu_f(zv.x);
  float g1 = (yf.y + yb.y)*silu_f(zv.y);
  float g2 = (yf.z + yb.z)*silu_f(zv.z);
  float g3 = (yf.w + yb.w)*silu_f(zv.w);
  ushort4 h, l;
  h.x = f2bf(g0); l.x = f2bf(g0 - b2f(h.x));
  h.y = f2bf(g1); l.y = f2bf(g1 - b2f(h.y));
  h.z = f2bf(g2); l.z = f2bf(g2 - b2f(h.z));
  h.w = f2bf(g3); l.w = f2bf(g3 - b2f(h.w));
  *(ushort4*)(gHi + (size_t)row*DI + c) = h;
  *(ushort4*)(gLo + (size_t)row*DI + c) = l;
}

// ---- generic pre-split-bf16 MFMA GEMM: C(M,N) (+)= A(M,K) @ B(N,K)^T ----
// 64x64 tile, 4 waves as 2x2 of 32x32, padded LDS. 3 MFMAs (hi*hi+lo*hi+hi*lo).
__global__ __launch_bounds__(256) void gemm_bf16(const u16* __restrict__ Ahi_g,
    const u16* __restrict__ Alo_g, int As, const u16* __restrict__ Bhi_g,
    const u16* __restrict__ Blo_g, int Bs, float* __restrict__ C, int Cs,
    int K, int addFlag){
  __shared__ __align__(16) u16 Ah[64*LDST], Al[64*LDST], Bh[64*LDST], Bl[64*LDST];
  int bm = blockIdx.y*64, bn = blockIdx.x*64;
  int t = threadIdx.x;
  int sr = t >> 2, sc8 = (t & 3)*8;
  int lane = t & 63, wv = t >> 6, ml = lane & 15, quad = lane >> 4;
  int mq = wv >> 1, nq = wv & 1;
  f4v acc[2][2] = {};
  for (int k0 = 0; k0 < K; k0 += 32){
    *(uint4*)&Ah[sr*LDST + sc8] = *(const uint4*)(Ahi_g + (size_t)(bm + sr)*As + k0 + sc8);
    *(uint4*)&Al[sr*LDST + sc8] = *(const uint4*)(Alo_g + (size_t)(bm + sr)*As + k0 + sc8);
    *(uint4*)&Bh[sr*LDST + sc8] = *(const uint4*)(Bhi_g + (size_t)(bn + sr)*Bs + k0 + sc8);
    *(uint4*)&Bl[sr*LDST + sc8] = *(const uint4*)(Blo_g + (size_t)(bn + sr)*Bs + k0 + sc8);
    __syncthreads();
    s8v ah[2], al2[2], bh2[2], bl2[2];
#pragma unroll
    for (int mt = 0; mt < 2; ++mt){
      int row = mq*32 + mt*16 + ml;
      ah[mt]  = *(s8v*)&Ah[row*LDST + quad*8];
      al2[mt] = *(s8v*)&Al[row*LDST + quad*8];
    }
#pragma unroll
    for (int nt = 0; nt < 2; ++nt){
      int col = nq*32 + nt*16 + ml;
      bh2[nt] = *(s8v*)&Bh[col*LDST + quad*8];
      bl2[nt] = *(s8v*)&Bl[col*LDST + quad*8];
    }
#pragma unroll
    for (int mt = 0; mt < 2; ++mt)
#pragma unroll
      for (int nt = 0; nt < 2; ++nt){
        acc[mt][nt] = __builtin_amdgcn_mfma_f32_16x16x32_bf16(ah[mt],  bh2[nt], acc[mt][nt], 0, 0, 0);
        acc[mt][nt] = __builtin_amdgcn_mfma_f32_16x16x32_bf16(al2[mt], bh2[nt], acc[mt][nt], 0, 0, 0);
        acc[mt][nt] = __builtin_amdgcn_mfma_f32_16x16x32_bf16(ah[mt],  bl2[nt], acc[mt][nt], 0, 0, 0);
      }
    __syncthreads();
  }
#pragma unroll
  for (int mt = 0; mt < 2; ++mt)
#pragma unroll
    for (int nt = 0; nt < 2; ++nt)
#pragma unroll
      for (int r = 0; r < 4; ++r){
        float* cp = C + (size_t)(bm + mq*32 + mt*16 + quad*4 + r)*Cs +
                    bn + nq*32 + nt*16 + ml;
        if (addFlag) *cp += acc[mt][nt][r];
        else         *cp  = acc[mt][nt][r];
      }
}

// ---- fused conv+silu -> xproj -> dtproj+softplus; block per (dir,b, 4 l's) ----
__global__ __launch_bounds__(256) void fused_cxd(const float* __restrict__ xz,
    const float* __restrict__ cwF, const float* __restrict__ cbF,
    const float* __restrict__ cwB, const float* __restrict__ cbB,
    const float* __restrict__ xwF, const float* __restrict__ xwB,
    const float* __restrict__ dtwF, const float* __restrict__ dtbF,
    const float* __restrict__ dtwB, const float* __restrict__ dtbB,
    int cwOff, int cbOff, int xwOff, int dtwOff, int dtbOff,
    float* __restrict__ u, float* __restrict__ xdbl, float* __restrict__ dtout){
  __shared__ float us[4*1024];
  __shared__ float part[16*64];
  __shared__ float dtr[4*32];
  int blk = blockIdx.x;
  int dir = blk >> 8, rem = blk & 255, b = rem >> 6, lg = rem & 63;
  int l0 = lg*4;
  const float* cw  = dir ? cwB  : cwF;
  const float* cb  = dir ? cbB  : cbF;
  const float* xw  = dir ? xwB  : xwF;
  const float* dtw = dir ? dtwB : dtwF;
  const float* dtb = dir ? dtbB : dtbF;
  int t = threadIdx.x;
  int rbase = (dir*BB + b)*LL;
  for (int dd = 0; dd < 4; ++dd){
    int d = t + dd*256;
    float4 w4 = *(const float4*)(cw + cwOff + d*4);
    float wf[4] = {w4.x, w4.y, w4.z, w4.w};
    float bias = cb[cbOff + d];
#pragma unroll
    for (int r = 0; r < 4; ++r){
      int l = l0 + r;
      float acc = bias;
#pragma unroll
      for (int k = 0; k < 4; ++k){
        int li = l + k - 3;
        if (li >= 0){
          int sl = dir ? (LL-1-li) : li;
          acc = fmaf(xz[(size_t)(b*LL + sl)*2048 + d], wf[k], acc);
        }
      }
      float uval = silu_f(acc);
      us[r*1024 + d] = uval;
      u[(size_t)(rbase + l)*DI + d] = uval;
    }
  }
  __syncthreads();
  {
    int e = t & 63, pr = t >> 6;
    float accs[4] = {};
    const float* wr = xw + xwOff + (size_t)e*1024 + pr*256;
    for (int i = 0; i < 256; i += 8){
      float4 w0 = *(const float4*)(wr + i);
      float4 w1 = *(const float4*)(wr + i + 4);
      float wf[8] = {w0.x,w0.y,w0.z,w0.w,w1.x,w1.y,w1.z,w1.w};
#pragma unroll
      for (int r = 0; r < 4; ++r){
        const float* ub = us + r*1024 + pr*256 + i;
#pragma unroll
        for (int j = 0; j < 8; ++j)
          accs[r] = fmaf(ub[j], wf[j], accs[r]);
      }
    }
#pragma unroll
    for (int r = 0; r < 4; ++r) part[(pr*4 + r)*64 + e] = accs[r];
  }
  __syncthreads();
  {
    int r = t >> 6, e = t & 63;
    float v = part[(0*4+r)*64+e] + part[(1*4+r)*64+e] +
              part[(2*4+r)*64+e] + part[(3*4+r)*64+e];
    xdbl[(size_t)(rbase + l0 + r)*64 + e] = v;
    if (e < 32) dtr[r*32 + e] = v;
  }
  __syncthreads();
  for (int dd = 0; dd < 4; ++dd){
    int d = t + dd*256;
    float bias = dtb[dtbOff + d];
    float accs[4] = {bias, bias, bias, bias};
    const float* wr = dtw + dtwOff + (size_t)d*32;
    for (int i = 0; i < 32; i += 8){
      float4 w0 = *(const float4*)(wr + i);
      float4 w1 = *(const float4*)(wr + i + 4);
      float wf[8] = {w0.x,w0.y,w0.z,w0.w,w1.x,w1.y,w1.z,w1.w};
#pragma unroll
      for (int r = 0; r < 4; ++r)
#pragma unroll
        for (int j = 0; j < 8; ++j)
          accs[r] = fmaf(dtr[r*32 + i + j], wf[j], accs[r]);
    }
#pragma unroll
    for (int r = 0; r < 4; ++r){
      float sv = accs[r];
      dtout[(size_t)(rbase + l0 + r)*DI + d] = (sv > 15.f) ? sv : log1pf(__expf(sv));
    }
  }
}

// ---- coalesced LDS-tiled selective scan ----
__global__ __launch_bounds__(256) void scan_coal(const float* __restrict__ dt,
    const float* __restrict__ u, const float* __restrict__ xd,
    const float* __restrict__ AlogF, const float* __restrict__ AlogB,
    const float* __restrict__ DF, const float* __restrict__ DB,
    int aOff, int dOff, float* __restrict__ y){
  __shared__ __align__(16) float dtuT[16][516];  // [d][(dt,u) per l], pad rows
  __shared__ __align__(16) float BCT[16][516];   // [s][(B,C) per l]
  __shared__ __align__(16) float ytile[128][16];
  int blk = blockIdx.x;
  int dir = blk >> 8, b = (blk >> 6) & 3, dg = blk & 63;
  int t = threadIdx.x;
  int rbase = (dir*BB + b)*LL;
  const float* Alog = dir ? AlogB : AlogF;
  const float* Dpt  = dir ? DB : DF;
  {
    int q = t & 3, lb = t >> 2;
    for (int pass = 0; pass < 4; ++pass){
      int l = pass*64 + lb;
      float4 dv = *(const float4*)(dt + (size_t)(rbase + l)*DI + dg*16 + q*4);
      float4 uv = *(const float4*)(u  + (size_t)(rbase + l)*DI + dg*16 + q*4);
      float2 p0 = {dv.x, uv.x}, p1 = {dv.y, uv.y}, p2 = {dv.z, uv.z}, p3 = {dv.w, uv.w};
      *(float2*)&dtuT[q*4+0][l*2] = p0;
      *(float2*)&dtuT[q*4+1][l*2] = p1;
      *(float2*)&dtuT[q*4+2][l*2] = p2;
      *(float2*)&dtuT[q*4+3][l*2] = p3;
    }
  }
  {
    int h8 = t & 7, lb = t >> 3;
    for (int pass = 0; pass < 8; ++pass){
      int l = pass*32 + lb;
      float4 v = *(const float4*)(xd + (size_t)(rbase + l)*64 + 32 + h8*4);
      if (h8 < 4){
        int s0 = h8*4;
        BCT[s0+0][l*2] = v.x; BCT[s0+1][l*2] = v.y;
        BCT[s0+2][l*2] = v.z; BCT[s0+3][l*2] = v.w;
      } else {
        int s0 = (h8-4)*4;
        BCT[s0+0][l*2+1] = v.x; BCT[s0+1][l*2+1] = v.y;
        BCT[s0+2][l*2+1] = v.z; BCT[s0+3][l*2+1] = v.w;
      }
    }
  }
  int s = t & 15, dl = t >> 4;
  float Av = -__expf(Alog[aOff + dg*256 + t]);
  float Dp = Dpt[dOff + dg*16 + dl];
  __syncthreads();
  float h = 0.f;
  for (int half = 0; half < 2; ++half){
    for (int l0 = half*128; l0 < half*128 + 128; l0 += 4){
      float4 du01 = *(const float4*)&dtuT[dl][l0*2];
      float4 du23 = *(const float4*)&dtuT[dl][l0*2 + 4];
      float4 bc01 = *(const float4*)&BCT[s][l0*2];
      float4 bc23 = *(const float4*)&BCT[s][l0*2 + 4];
      float dtv[4] = {du01.x, du01.z, du23.x, du23.z};
      float uv[4]  = {du01.y, du01.w, du23.y, du23.w};
      float Bv[4]  = {bc01.x, bc01.z, bc23.x, bc23.z};
      float Cv[4]  = {bc01.y, bc01.w, bc23.y, bc23.w};
#pragma unroll
      for (int i = 0; i < 4; ++i){
        float a = __expf(dtv[i] * Av);
        h = fmaf(a, h, dtv[i]*uv[i]*Bv[i]);
        float p = h * Cv[i];
        float sum = row_sum16(p);
        if (s == 15){
          int lr = (l0 + i) & 127;
          ytile[lr][dl] = fmaf(uv[i], Dp, sum);
        }
      }
    }
    __syncthreads();
    {
      int d4 = t & 3, lh = t >> 2;
      for (int pass = 0; pass < 2; ++pass){
        int lr = pass*64 + lh;
        int l = half*128 + lr;
        int lo = dir ? (255 - l) : l;
        float4 vv = *(const float4*)&ytile[lr][d4*4];
        *(float4*)(y + (size_t)(rbase + lo)*DI + dg*16 + d4*4) = vv;
      }
    }
    __syncthreads();
  }
}

// ---- final LayerNorm ----
__global__ __launch_bounds__(256) void ln_kernel(const float* __restrict__ x,
    const float* __restrict__ w, const float* __restrict__ bias,
    float* __restrict__ y){
  __shared__ float sc[8];
  int row = blockIdx.x, t = threadIdx.x;
  const float* xr = x + (size_t)row*DM;
  float v0 = xr[t], v1 = xr[t + 256];
  float s = v0 + v1, ss = v0*v0 + v1*v1;
  block_reduce2(s, ss, sc, 4);
  float mean = s * (1.f/512.f);
  float var = ss * (1.f/512.f) - mean*mean;
  float inv = rsqrtf(var + 1e-5f);
  float* yr = y + (size_t)row*DM;
  yr[t]       = (v0 - mean)*inv*w[t]       + bias[t];
  yr[t + 256] = (v1 - mean)*inv*w[t + 256] + bias[t + 256];
}

// ---- pool: mean over L, coalesced; 32 blocks (4 b x 8 d-groups) ----
__global__ __launch_bounds__(256) void pool_kernel(const float* __restrict__ hn,
    float* __restrict__ feat){
  __shared__ float part[4][64];
  int b = blockIdx.x >> 3, dg = blockIdx.x & 7;
  int t = threadIdx.x, dl = t & 63, lq = t >> 6;
  const float* p = hn + (size_t)(b*256 + lq*64)*512 + dg*64 + dl;
  float s = 0.f;
#pragma unroll 4
  for (int i = 0; i < 64; ++i) s += p[(size_t)i*512];
  part[lq][dl] = s;
  __syncthreads();
  if (t < 64)
    feat[b*512 + dg*64 + t] =
        (part[0][t] + part[1][t] + part[2][t] + part[3][t]) * (1.f/256.f);
}

// ---- head: LN + fc1/relu + fc2; 4 blocks ----
__global__ __launch_bounds__(512) void head_kernel(const float* __restrict__ feat,
    const float* __restrict__ lnw, const float* __restrict__ lnb,
    const float* __restrict__ fc1w, const float* __restrict__ fc1b,
    const float* __restrict__ fc2w, const float* __restrict__ fc2b,
    float* __restrict__ out){
  __shared__ float sc[16];
  __shared__ float cbuf[512];
  __shared__ float rbuf[512];
  int b = blockIdx.x, t = threadIdx.x;
  float v = feat[b*512 + t];
  float s = v, ss = v*v;
  block_reduce2(s, ss, sc, 8);
  float mean = s * (1.f/512.f);
  float var = ss * (1.f/512.f) - mean*mean;
  float inv = rsqrtf(var + 1e-5f);
  cbuf[t] = (v - mean)*inv*lnw[t] + lnb[t];
  __syncthreads();
  float a = fc1b[t];
  const float* w1 = fc1w + (size_t)t*512;
  for (int i = 0; i < 512; i += 8){
    float4 w0 = *(const float4*)(w1 + i);
    float4 w4 = *(const float4*)(w1 + i + 4);
    float wf[8] = {w0.x,w0.y,w0.z,w0.w,w4.x,w4.y,w4.z,w4.w};
#pragma unroll
    for (int j = 0; j < 8; ++j) a = fmaf(cbuf[i + j], wf[j], a);
  }
  rbuf[t] = fmaxf(a, 0.f);
  __syncthreads();
  if (t < 10){
    float a2 = fc2b[t];
    const float* w2 = fc2w + (size_t)t*512;
    for (int i = 0; i < 512; ++i) a2 = fmaf(rbuf[i], w2[i], a2);
    out[b*10 + t] = a2;
  }
}

extern "C" void kernel_launch(void* const* d_in, const int* in_sizes, int n_in,
                              void* d_out, int out_size, void* d_ws, size_t ws_size,
                              hipStream_t stream) {
  (void)in_sizes; (void)n_in; (void)out_size; (void)ws_size;
  const float* x          = (const float*)d_in[0];
  const float* patch_w    = (const float*)d_in[1];
  const float* patch_b    = (const float*)d_in[2];
  const float* in_proj_w  = (const float*)d_in[3];
  const float* conv_w_f   = (const float*)d_in[4];
  const float* conv_b_f   = (const float*)d_in[5];
  const float* xproj_w_f  = (const float*)d_in[6];
  const float* dtproj_w_f = (const float*)d_in[7];
  const float* dtproj_b_f = (const float*)d_in[8];
  const float* A_log_f    = (const float*)d_in[9];
  const float* D_f        = (const float*)d_in[10];
  const float* conv_w_b   = (const float*)d_in[11];
  const float* conv_b_b   = (const float*)d_in[12];
  const float* xproj_w_b  = (const float*)d_in[13];
  const float* dtproj_w_b = (const float*)d_in[14];
  const float* dtproj_b_b = (const float*)d_in[15];
  const float* A_log_b    = (const float*)d_in[16];
  const float* D_b        = (const float*)d_in[17];
  const float* out_proj_w = (const float*)d_in[18];
  const float* norm_w     = (const float*)d_in[19];
  const float* norm_b     = (const float*)d_in[20];
  const float* normf_w    = (const float*)d_in[21];
  const float* normf_b    = (const float*)d_in[22];
  const float* ln_w       = (const float*)d_in[23];
  const float* ln_b       = (const float*)d_in[24];
  const float* fc1_w      = (const float*)d_in[25];
  const float* fc1_b      = (const float*)d_in[26];
  const float* fc2_w      = (const float*)d_in[27];
  const float* fc2_b      = (const float*)d_in[28];

  float* ws   = (float*)d_ws;
  float* hbuf = ws;                 // 524288
  float* xz   = ws + 524288;        // 2097152
  float* ubuf = ws + 2621440;       // 2097152 (2 dirs); gHi/gLo reuse this after scan
  float* xdbl = ws + 4718592;       // 131072  (2 dirs)
  float* dtb  = ws + 4849664;       // 2097152 (2 dirs)
  float* ybuf = ws + 6946816;       // 2097152 (2 dirs)
  float* hn   = ws + 9043968;       // 524288; xnHi/xnLo reuse this during layers
  u16*   inHi = (u16*)(ws + 9568256);   // 1048576 u16
  u16*   inLo = (u16*)(ws + 10092544);  // 1048576 u16
  u16*   outHi= (u16*)(ws + 10616832);  // 524288 u16
  u16*   outLo= (u16*)(ws + 10878976);  // 524288 u16
  float* feat = ws + 11141120;          // 2048
  u16*   xnHi = (u16*)hn;               // 524288 u16 (dead until final ln)
  u16*   xnLo = (u16*)(ws + 9043968 + 262144);
  u16*   gHi  = (u16*)ubuf;             // 1048576 u16 (dead after scan)
  u16*   gLo  = (u16*)(ws + 2621440 + 524288);

  patch_embed<<<256, 256, 0, stream>>>(x, patch_w, patch_b, hbuf);
  for (int i = 0; i < 4; ++i){
    convert_w<<<1536, 256, 0, stream>>>(in_proj_w + (size_t)i*1048576,
                                        out_proj_w + (size_t)i*524288,
                                        inHi, inLo, outHi, outLo);
    prep_ln<<<1024, 256, 0, stream>>>(hbuf, norm_w, norm_b, i*512, xnHi, xnLo);
    gemm_bf16<<<dim3(32, 16), 256, 0, stream>>>(
        xnHi, xnLo, 512, inHi, inLo, 512, xz, 2048, 512, 0);
    fused_cxd<<<512, 256, 0, stream>>>(
        xz, conv_w_f, conv_b_f, conv_w_b, conv_b_b, xproj_w_f, xproj_w_b,
        dtproj_w_f, dtproj_b_f, dtproj_w_b, dtproj_b_b,
        i*4096, i*1024, i*65536, i*32768, i*1024, ubuf, xdbl, dtb);
    scan_coal<<<512, 256, 0, stream>>>(
        dtb, ubuf, xdbl, A_log_f, A_log_b, D_f, D_b, i*16384, i*1024, ybuf);
    prep_gate<<<1024, 256, 0, stream>>>(ybuf, xz, gHi, gLo);
    gemm_bf16<<<dim3(8, 16), 256, 0, stream>>>(
        gHi, gLo, 1024, outHi, outLo, 1024, hbuf, 512, 1024, 1);
  }
  ln_kernel<<<1024, 256, 0, stream>>>(hbuf, normf_w, normf_b, hn);
  pool_kernel<<<32, 256, 0, stream>>>(hn, feat);
  head_kernel<<<4, 512, 0, stream>>>(feat, ln_w, ln_b, fc1_w, fc1_b, fc2_w, fc2_b,
                                     (float*)d_out);
}